// Round 14
// baseline (743.378 us; speedup 1.0000x reference)
//
#include <hip/hip_runtime.h>
#include <math.h>

// StreamingDPM: probs = softmax([ -0.5*(D log2pi + logdet_k + quad_nk) + log_prior_k | log_new ])
// N=4096 D=256 K=64, out [N, K+1] fp32.
//
// ws layout (floats):
//   S    : K*D*D  (sweep result; holds -Sigma^{-1} after all steps)
//   cA   : K      (log_prior_k - 0.5*(D log2pi + logdet_k))
//   ldp  : 4*K    (per-block-step logdet partials)
//   lp   : N*K    (log-probs before softmax)
// wv (= S_k * mu_k, [K][D]) lives in the OUTPUT buffer temporarily (quad reads
// it before softmax overwrites out; stream-ordered, safe).
//
// Fused sweep (7 launches total, was 11):
//   init_kernel      : sweep P0 from covs -> write -P0^{-1} into S[J0,J0] diag.
//   step_kernel(bs)  : grid (K,3), slices t != bs.
//     - Pl(bs) staged from S[J_bs,J_bs] diag (the final matrix's M[J,J] =
//       -P^{-1}, so the diag doubles as the Plbuf).
//     - defer slice (t==bs-1): reconstructs the deferred J-column values
//       (Pp = diag; Cprev from srcC), then applies the rank-64 update on top.
//       *** srcC = covs when bs==1 (S[:,J0] off-diag was never written --
//       reading Sk there was the r13 tripwire bug: garbage on call 1, stale
//       values on later calls), Sk when bs>=2 (last written at launch bs-2,
//       i.e. correct pre-step values). ***
//     - carrier slice (t==bs+1): after writing its updated slice, sweeps the
//       new pivot block (stashed in LDS) and writes -P^{-1} to the diag.
//   final_kernel     : J3 defer (values kept in LDS) + wv = S*mu + cA.
// Single-launch races: slices are column-disjoint; barrier separates all
// global reads of a block's own columns from its writes; diag blocks are
// single-writer per launch. (Cooperative fusion measured WORSE: ~70us/sync.)

#define DD 256
#define KC 64
#define NPTS 4096
#define NT 64
#define BB 64          // sweep block size
#define KG 4           // clusters per quad block

// ---------------- Kernel 1a: initial pivot sweep (P0 from covs) --------------
__global__ __launch_bounds__(512) void init_kernel(
    const float* __restrict__ covs, float* __restrict__ S,
    float* __restrict__ ldp)
{
  const int k = blockIdx.x;
  const int tid = threadIdx.x;
  const float* Ck = covs + (size_t)k * DD * DD;
  float* Sk = S + (size_t)k * DD * DD;

  __shared__ __align__(16) float pivc[2][BB];
  __shared__ __align__(16) float pivr[2][BB];

  const int pr = tid >> 3;
  const int pc = (tid & 7) * 8;

  float v[8];
  {
    float4 a4 = *reinterpret_cast<const float4*>(&Ck[(size_t)pr * DD + pc]);
    float4 b4 = *reinterpret_cast<const float4*>(&Ck[(size_t)pr * DD + pc + 4]);
    v[0] = a4.x; v[1] = a4.y; v[2] = a4.z; v[3] = a4.w;
    v[4] = b4.x; v[5] = b4.y; v[6] = b4.z; v[7] = b4.w;
  }
  if (pc == 0) pivc[0][pr] = v[0];
  if (pr == 0) {
    #pragma unroll
    for (int e = 0; e < 8; ++e) pivr[0][pc + e] = v[e];
  }
  __syncthreads();

  float ld = 0.0f;
  #pragma unroll 1
  for (int p = 0; p < BB; ++p) {
    const int cur = p & 1, nxt = cur ^ 1;
    const float d = pivc[cur][p];
    const float inv_d = 1.0f / d;
    if (tid == 0) ld += logf(d);
    const float cr = pivc[cur][pr];
    float rw[8];
    *reinterpret_cast<float4*>(&rw[0]) = *reinterpret_cast<const float4*>(&pivr[cur][pc]);
    *reinterpret_cast<float4*>(&rw[4]) = *reinterpret_cast<const float4*>(&pivr[cur][pc + 4]);
    #pragma unroll
    for (int e = 0; e < 8; ++e) {
      float ge = fmaf(-inv_d * cr, rw[e], v[e]);              // general update
      if (pr == p)     ge = rw[e] * inv_d;                    // pivot row
      if (pc + e == p) ge = (pr == p) ? -inv_d : cr * inv_d;  // pivot col/diag
      v[e] = ge;
    }
    if (p < BB - 1) {
      if (pr == p + 1) {
        #pragma unroll
        for (int e = 0; e < 8; ++e) pivr[nxt][pc + e] = v[e];
      }
      if (pc <= p + 1 && p + 1 < pc + 8) pivc[nxt][pr] = v[p + 1 - pc];
    }
    __syncthreads();
  }

  // write -P0^{-1} into the S diagonal block (doubles as Plbuf)
  *reinterpret_cast<float4*>(&Sk[(size_t)pr * DD + pc]) =
      *reinterpret_cast<const float4*>(&v[0]);
  *reinterpret_cast<float4*>(&Sk[(size_t)pr * DD + pc + 4]) =
      *reinterpret_cast<const float4*>(&v[4]);
  if (tid == 0) ldp[k] = ld;
}

// ---------------- Kernel 1b: fused step (update + inline defer + carrier) ----
__global__ __launch_bounds__(512) void step_kernel(
    const float* __restrict__ covs, float* __restrict__ S,
    float* __restrict__ ldp, int bs)
{
  const int k = blockIdx.x;
  const int si = blockIdx.y;
  const int tid = threadIdx.x;
  const int t = si + (si >= bs ? 1 : 0);
  const int c0 = t * BB;
  const int j0 = bs * BB;
  const int j0p = (bs - 1) * BB;                  // valid when isDefer
  const bool isDefer = (bs >= 1) && (t == bs - 1);
  const bool isCarrier = (bs <= 2) && (t == bs + 1);
  float* Sk = S + (size_t)k * DD * DD;
  const float* srcQ = (bs == 0) ? (covs + (size_t)k * DD * DD) : (const float*)Sk;
  // Cprev source for the defer: pre-step-(bs-1) values of columns J_{bs-1}.
  // bs==1: those are covs columns J0 (S[:,J0] off-diag never written!).
  // bs>=2: S holds them (last written at launch bs-2).
  const float* srcC = (bs == 1) ? (covs + (size_t)k * DD * DD) : (const float*)Sk;

  __shared__ __align__(16) float Pl[BB][BB + 4];  // -P_bs^{-1}
  __shared__ __align__(16) float SJ[BB][BB + 4];  // M_bs[J, slice]; later Pnew
  __shared__ __align__(16) float Tl[BB][BB + 4];  // T' = Pl * SJ
  __shared__ __align__(16) float Pp[BB][BB + 4];  // -P_{bs-1}^{-1} (defer)
  __shared__ __align__(16) float pivc[2][BB];
  __shared__ __align__(16) float pivr[2][BB];

  // ---- phase 0: stage Pl (and Pprev for the defer slice) from S diagonals
  {
    const int rr = tid >> 3;
    const int cc = (tid & 7) * 8;
    *reinterpret_cast<float4*>(&Pl[rr][cc]) =
        *reinterpret_cast<const float4*>(&Sk[(size_t)(j0 + rr) * DD + j0 + cc]);
    *reinterpret_cast<float4*>(&Pl[rr][cc + 4]) =
        *reinterpret_cast<const float4*>(&Sk[(size_t)(j0 + rr) * DD + j0 + cc + 4]);
    if (isDefer) {
      *reinterpret_cast<float4*>(&Pp[rr][cc]) =
          *reinterpret_cast<const float4*>(&Sk[(size_t)(j0p + rr) * DD + j0p + cc]);
      *reinterpret_cast<float4*>(&Pp[rr][cc + 4]) =
          *reinterpret_cast<const float4*>(&Sk[(size_t)(j0p + rr) * DD + j0p + cc + 4]);
    }
  }
  __syncthreads();

  // ---- phase 1: SJ = M_bs[J_bs, slice t]
  {
    const int rr = tid >> 3;
    const int cc = (tid & 7) * 8;
    if (!isDefer) {
      *reinterpret_cast<float4*>(&SJ[rr][cc]) =
          *reinterpret_cast<const float4*>(&srcQ[(size_t)(j0 + rr) * DD + c0 + cc]);
      *reinterpret_cast<float4*>(&SJ[rr][cc + 4]) =
          *reinterpret_cast<const float4*>(&srcQ[(size_t)(j0 + rr) * DD + c0 + cc + 4]);
    } else {
      // defer slice: M_bs[J_bs, J_{bs-1}] = -(Cprev[J_bs rows] * Pp)
      float Crwp[BB];
      #pragma unroll
      for (int p = 0; p < BB; p += 4) {
        float4 cv = *reinterpret_cast<const float4*>(&srcC[(size_t)(j0 + rr) * DD + j0p + p]);
        Crwp[p] = cv.x; Crwp[p + 1] = cv.y; Crwp[p + 2] = cv.z; Crwp[p + 3] = cv.w;
      }
      float acc[8] = {0.f, 0.f, 0.f, 0.f, 0.f, 0.f, 0.f, 0.f};
      #pragma unroll
      for (int p = 0; p < BB; ++p) {
        float4 t0 = *reinterpret_cast<const float4*>(&Pp[p][cc]);
        float4 t1 = *reinterpret_cast<const float4*>(&Pp[p][cc + 4]);
        acc[0] = fmaf(Crwp[p], t0.x, acc[0]);
        acc[1] = fmaf(Crwp[p], t0.y, acc[1]);
        acc[2] = fmaf(Crwp[p], t0.z, acc[2]);
        acc[3] = fmaf(Crwp[p], t0.w, acc[3]);
        acc[4] = fmaf(Crwp[p], t1.x, acc[4]);
        acc[5] = fmaf(Crwp[p], t1.y, acc[5]);
        acc[6] = fmaf(Crwp[p], t1.z, acc[6]);
        acc[7] = fmaf(Crwp[p], t1.w, acc[7]);
      }
      #pragma unroll
      for (int e = 0; e < 8; ++e) SJ[rr][cc + e] = -acc[e];
    }
  }
  __syncthreads();

  // ---- phase 2: T' = Pl * SJ  (thread: col c, 8 rows)
  {
    const int c = tid & 63;
    const int rg = (tid >> 6) * 8;
    float tv[8];
    #pragma unroll
    for (int r = 0; r < 8; ++r) tv[r] = 0.0f;
    for (int p = 0; p < BB; p += 4) {
      float s0 = SJ[p][c], s1 = SJ[p + 1][c], s2 = SJ[p + 2][c], s3 = SJ[p + 3][c];
      #pragma unroll
      for (int r = 0; r < 8; ++r) {
        float4 pv = *reinterpret_cast<const float4*>(&Pl[rg + r][p]);
        tv[r] = fmaf(pv.x, s0, fmaf(pv.y, s1, fmaf(pv.z, s2, fmaf(pv.w, s3, tv[r]))));
      }
    }
    #pragma unroll
    for (int r = 0; r < 8; ++r) Tl[rg + r][c] = tv[r];
  }
  __syncthreads();

  // ---- phase 3a: compute base Q (reads of S cols c0 happen HERE, pre-barrier)
  const int r = tid & 255;
  const int h = (tid >> 8) * 32;
  const bool inJ = (r >= j0) && (r < j0 + BB);
  float q[32];
  if (!inJ) {
    if (!isDefer) {
      #pragma unroll
      for (int c = 0; c < 32; c += 4) {
        float4 v4 = *reinterpret_cast<const float4*>(&srcQ[(size_t)r * DD + c0 + h + c]);
        q[c] = v4.x; q[c + 1] = v4.y; q[c + 2] = v4.z; q[c + 3] = v4.w;
      }
    } else {
      const bool inJp = (r >= j0p) && (r < j0p + BB);
      if (inJp) {
        #pragma unroll
        for (int c = 0; c < 32; ++c) q[c] = Pp[r - j0p][h + c];
      } else {
        float Crwp[BB];
        #pragma unroll
        for (int p = 0; p < BB; p += 4) {
          float4 cv = *reinterpret_cast<const float4*>(&srcC[(size_t)r * DD + j0p + p]);
          Crwp[p] = cv.x; Crwp[p + 1] = cv.y; Crwp[p + 2] = cv.z; Crwp[p + 3] = cv.w;
        }
        #pragma unroll
        for (int c = 0; c < 32; ++c) q[c] = 0.0f;
        #pragma unroll
        for (int p = 0; p < BB; ++p) {
          const float cp = Crwp[p];
          #pragma unroll
          for (int c = 0; c < 32; c += 4) {
            float4 pv = *reinterpret_cast<const float4*>(&Pp[p][h + c]);
            q[c]     = fmaf(cp, pv.x, q[c]);
            q[c + 1] = fmaf(cp, pv.y, q[c + 1]);
            q[c + 2] = fmaf(cp, pv.z, q[c + 2]);
            q[c + 3] = fmaf(cp, pv.w, q[c + 3]);
          }
        }
        #pragma unroll
        for (int c = 0; c < 32; ++c) q[c] = -q[c];
      }
    }
  }
  __syncthreads();  // ALL reads of columns c0 complete before any write

  // ---- phase 3b: apply rank-64 update, write slice (and stash Pnew if carrier)
  if (inJ) {
    #pragma unroll
    for (int c = 0; c < 32; c += 4) {
      float4 tv4 = *reinterpret_cast<const float4*>(&Tl[r - j0][h + c]);
      float4 o = {-tv4.x, -tv4.y, -tv4.z, -tv4.w};
      *reinterpret_cast<float4*>(&Sk[(size_t)r * DD + c0 + h + c]) = o;
    }
  } else {
    float Crw[BB];
    #pragma unroll
    for (int p = 0; p < BB; p += 4) {
      float4 cv = *reinterpret_cast<const float4*>(&srcQ[(size_t)r * DD + j0 + p]);
      Crw[p] = cv.x; Crw[p + 1] = cv.y; Crw[p + 2] = cv.z; Crw[p + 3] = cv.w;
    }
    #pragma unroll
    for (int c = 0; c < 32; c += 4) {
      float a0 = q[c], a1 = q[c + 1], a2 = q[c + 2], a3 = q[c + 3];
      #pragma unroll
      for (int p = 0; p < BB; ++p) {
        float4 tv4 = *reinterpret_cast<const float4*>(&Tl[p][h + c]);
        a0 = fmaf(Crw[p], tv4.x, a0);
        a1 = fmaf(Crw[p], tv4.y, a1);
        a2 = fmaf(Crw[p], tv4.z, a2);
        a3 = fmaf(Crw[p], tv4.w, a3);
      }
      float4 o = {a0, a1, a2, a3};
      *reinterpret_cast<float4*>(&Sk[(size_t)r * DD + c0 + h + c]) = o;
      if (isCarrier && r >= c0 && r < c0 + BB)
        *reinterpret_cast<float4*>(&SJ[r - c0][h + c]) = o;  // stash new pivot
    }
  }

  // ---- phase 4 (carrier only): sweep the new pivot block, write to diag
  if (isCarrier) {
    __syncthreads();  // Pnew (in SJ) fully stashed
    const int pr = tid >> 3;
    const int pc = (tid & 7) * 8;
    float v[8];
    *reinterpret_cast<float4*>(&v[0]) = *reinterpret_cast<const float4*>(&SJ[pr][pc]);
    *reinterpret_cast<float4*>(&v[4]) = *reinterpret_cast<const float4*>(&SJ[pr][pc + 4]);
    if (pc == 0) pivc[0][pr] = v[0];
    if (pr == 0) {
      #pragma unroll
      for (int e = 0; e < 8; ++e) pivr[0][pc + e] = v[e];
    }
    __syncthreads();

    float ld = 0.0f;
    #pragma unroll 1
    for (int p = 0; p < BB; ++p) {
      const int cur = p & 1, nxt = cur ^ 1;
      const float d = pivc[cur][p];
      const float inv_d = 1.0f / d;
      if (tid == 0) ld += logf(d);
      const float cr = pivc[cur][pr];
      float rw[8];
      *reinterpret_cast<float4*>(&rw[0]) = *reinterpret_cast<const float4*>(&pivr[cur][pc]);
      *reinterpret_cast<float4*>(&rw[4]) = *reinterpret_cast<const float4*>(&pivr[cur][pc + 4]);
      #pragma unroll
      for (int e = 0; e < 8; ++e) {
        float ge = fmaf(-inv_d * cr, rw[e], v[e]);
        if (pr == p)     ge = rw[e] * inv_d;
        if (pc + e == p) ge = (pr == p) ? -inv_d : cr * inv_d;
        v[e] = ge;
      }
      if (p < BB - 1) {
        if (pr == p + 1) {
          #pragma unroll
          for (int e = 0; e < 8; ++e) pivr[nxt][pc + e] = v[e];
        }
        if (pc <= p + 1 && p + 1 < pc + 8) pivc[nxt][pr] = v[p + 1 - pc];
      }
      __syncthreads();
    }

    *reinterpret_cast<float4*>(&Sk[(size_t)(c0 + pr) * DD + c0 + pc]) =
        *reinterpret_cast<const float4*>(&v[0]);
    *reinterpret_cast<float4*>(&Sk[(size_t)(c0 + pr) * DD + c0 + pc + 4]) =
        *reinterpret_cast<const float4*>(&v[4]);
    if (tid == 0) ldp[(bs + 1) * KC + k] = ld;
  }
}

// ---------------- Kernel 1c: final J3 defer + wv = S*mu + cA -----------------
__global__ __launch_bounds__(512) void final_kernel(
    float* __restrict__ S, const float* __restrict__ means,
    const float* __restrict__ counts, const int* __restrict__ n_points_p,
    const float* __restrict__ ldp, float* __restrict__ cA,
    float* __restrict__ wv)
{
  const int k = blockIdx.x;
  const int tid = threadIdx.x;
  float* Sk = S + (size_t)k * DD * DD;
  const int j3 = 3 * BB;  // 192

  __shared__ __align__(16) float Pl[BB][BB + 4];      // -P3^{-1} (= final diag)
  __shared__ __align__(16) float Dst[3 * BB][BB + 4]; // defer values rows 0..191
  __shared__ __align__(16) float mus[DD];
  __shared__ __align__(16) float red[2][DD];

  {
    const int rr = tid >> 3;
    const int cc = (tid & 7) * 8;
    *reinterpret_cast<float4*>(&Pl[rr][cc]) =
        *reinterpret_cast<const float4*>(&Sk[(size_t)(j3 + rr) * DD + j3 + cc]);
    *reinterpret_cast<float4*>(&Pl[rr][cc + 4]) =
        *reinterpret_cast<const float4*>(&Sk[(size_t)(j3 + rr) * DD + j3 + cc + 4]);
  }
  if (tid < DD) mus[tid] = means[(size_t)k * DD + tid];
  __syncthreads();

  // defer(3): rows r < 192: M4[r, J3] = -(C3[r] * Pl); keep a copy in LDS so
  // the wv pass never re-reads just-written global memory.
  {
    const int r = tid & 255;
    const int h = (tid >> 8) * 32;
    if (r < j3) {
      float Crw[BB];
      #pragma unroll
      for (int p = 0; p < BB; p += 4) {
        float4 cv = *reinterpret_cast<const float4*>(&Sk[(size_t)r * DD + j3 + p]);
        Crw[p] = cv.x; Crw[p + 1] = cv.y; Crw[p + 2] = cv.z; Crw[p + 3] = cv.w;
      }
      #pragma unroll
      for (int c = 0; c < 32; c += 4) {
        float a0 = 0.f, a1 = 0.f, a2 = 0.f, a3 = 0.f;
        #pragma unroll
        for (int p = 0; p < BB; ++p) {
          float4 pv = *reinterpret_cast<const float4*>(&Pl[p][h + c]);
          a0 = fmaf(Crw[p], pv.x, a0);
          a1 = fmaf(Crw[p], pv.y, a1);
          a2 = fmaf(Crw[p], pv.z, a2);
          a3 = fmaf(Crw[p], pv.w, a3);
        }
        float4 o = {-a0, -a1, -a2, -a3};
        *reinterpret_cast<float4*>(&Sk[(size_t)r * DD + j3 + h + c]) = o;
        *reinterpret_cast<float4*>(&Dst[r][h + c]) = o;
      }
    }
    // rows in J3: S[J3,J3] already holds Pl (= final value) -- nothing to do.
  }
  __syncthreads();

  // wv_j = sum_i S[i,j] * mu_i ; J3 columns read from LDS (Dst/Pl), others
  // from global (written in prior launches).
  {
    const int j = tid & 255;
    const int hp = tid >> 8;  // half: i in [hp*128, hp*128+128)
    float acc = 0.0f;
    if (j < j3) {
      const float* col = Sk + j;
      #pragma unroll 4
      for (int i = hp * 128; i < hp * 128 + 128; ++i)
        acc = fmaf(col[(size_t)i * DD], mus[i], acc);
    } else {
      const int jj = j - j3;
      if (hp == 0) {
        #pragma unroll 4
        for (int i = 0; i < 128; ++i) acc = fmaf(Dst[i][jj], mus[i], acc);
      } else {
        #pragma unroll 4
        for (int i = 128; i < 192; ++i) acc = fmaf(Dst[i][jj], mus[i], acc);
        #pragma unroll 4
        for (int i = 192; i < 256; ++i) acc = fmaf(Pl[i - 192][jj], mus[i], acc);
      }
    }
    red[hp][j] = acc;
  }
  __syncthreads();
  if (tid < DD) wv[(size_t)k * DD + tid] = red[0][tid] + red[1][tid];
  if (tid == 0) {
    float denom = (float)(*n_points_p) + 1.0f;  // ALPHA = 1
    float ld = ldp[k] + ldp[KC + k] + ldp[2 * KC + k] + ldp[3 * KC + k];
    // D*log(2*pi) = 256 * 1.8378770664093453
    cA[k] = logf(counts[k] / denom) - 0.5f * (470.49652900079047f + ld);
  }
}

// ---------------- Kernel 2: quad, wave-private barrier-free inner loop -------
// (r11 proven form: 407us, VALUBusy 74%, 88 VGPR, no spill. r8/r10/r12
//  established the global-S path caps at ~66-69% regardless of pipeline
//  depth -- LDS double-buffer with zero inner barriers is the best.)
__global__ __launch_bounds__(256) void quad_kernel(
    const float* __restrict__ X, const float* __restrict__ means,
    const float* __restrict__ S, const float* __restrict__ cA,
    const float* __restrict__ wv, float* __restrict__ lp)
{
  __shared__ __align__(16) float XT[DD][NT];        // (i,r) at XT[i][r ^ (((i>>2)&15)<<2)]
  __shared__ __align__(16) float Pw[4][2][4][68];   // wave-private S strips; qred alias
  __shared__ __align__(16) float muw[2][DD];        // mu_k, wv_k
  __shared__ __align__(16) float lpb[KG][NT];       // results, flushed at end

  const int tid = threadIdx.x;
  const int n0 = blockIdx.x * NT;
  const int k0 = blockIdx.y * KG;

  // stage X tile transposed + swizzled (once per block)
  #pragma unroll
  for (int q = 0; q < 16; ++q) {
    int f = q * 1024 + tid * 4;
    int r = f >> 8;
    int c = f & 255;
    float4 xv = *reinterpret_cast<const float4*>(X + (size_t)(n0 + r) * DD + c);
    int rs = r ^ (((c >> 2) & 15) << 2);
    XT[c + 0][rs] = xv.x;
    XT[c + 1][rs] = xv.y;
    XT[c + 2][rs] = xv.z;
    XT[c + 3][rs] = xv.w;
  }

  const int tn = tid & 7;          // n sub-tile: rows tn*8 .. +7
  const int tj = tid >> 3;         // j sub-tile: cols tj*8 .. +7
  const int wid = tid >> 6;        // wave id 0..3
  const int lane = tid & 63;
  const int g = (tid >> 3) & 7;    // tj within wave
  const int srow = lane >> 4;      // staging row within 4-row chunk
  const int scol = (lane & 15) * 4;// staging col (float4)

  #pragma unroll 1
  for (int kk = 0; kk < KG; ++kk) {
    const int k = k0 + kk;
    const float* Skw = S + (size_t)k * DD * DD + wid * 64;  // wave's col slice

    __syncthreads();  // prev k's qred readers done (Pw aliased); XT staged
    muw[0][tid] = means[(size_t)k * DD + tid];
    muw[1][tid] = wv[(size_t)k * DD + tid];

    // prologue: chunk 0 -> LDS buf 0; chunk 1 -> prefetch regs
    float4 st = *reinterpret_cast<const float4*>(Skw + (size_t)srow * DD + scol);
    *reinterpret_cast<float4*>(&Pw[wid][0][srow][scol]) = st;
    st = *reinterpret_cast<const float4*>(Skw + (size_t)(4 + srow) * DD + scol);

    float y[8][8];
    #pragma unroll
    for (int a = 0; a < 8; ++a)
      #pragma unroll
      for (int b = 0; b < 8; ++b) y[a][b] = 0.0f;

    #pragma unroll 1
    for (int ct = 0; ct < 64; ++ct) {
      const int cur = ct & 1;
      #pragma unroll
      for (int il = 0; il < 4; ++il) {
        const int i = ct * 4 + il;
        const int sw = ((i >> 2) & 15) << 2;
        float xv[8], pv[8];
        *reinterpret_cast<float4*>(&xv[0]) =
            *reinterpret_cast<const float4*>(&XT[i][(tn * 8) ^ sw]);
        *reinterpret_cast<float4*>(&xv[4]) =
            *reinterpret_cast<const float4*>(&XT[i][(tn * 8 + 4) ^ sw]);
        *reinterpret_cast<float4*>(&pv[0]) =
            *reinterpret_cast<const float4*>(&Pw[wid][cur][il][g * 8]);
        *reinterpret_cast<float4*>(&pv[4]) =
            *reinterpret_cast<const float4*>(&Pw[wid][cur][il][g * 8 + 4]);
        #pragma unroll
        for (int a = 0; a < 8; ++a)
          #pragma unroll
          for (int b = 0; b < 8; ++b)
            y[a][b] = fmaf(xv[a], pv[b], y[a][b]);
      }
      if (ct < 63) {
        // publish chunk ct+1 into the other buffer (wave-private, no barrier);
        // prefetch chunk ct+2 into regs (stays in flight across next 4 ils)
        *reinterpret_cast<float4*>(&Pw[wid][cur ^ 1][srow][scol]) = st;
        const int cnx = (ct + 2 < 64) ? (ct + 2) : 63;
        st = *reinterpret_cast<const float4*>(
            Skw + (size_t)(cnx * 4 + srow) * DD + scol);
      }
    }
    __syncthreads();  // muw visible; all waves done with Pw before qred reuse

    // epilogue: q'[n] = sum_j (x[n,j]-mu_j) * (y[n,j]-wv_j), partial over 8 j
    float s[8];
    #pragma unroll
    for (int a = 0; a < 8; ++a) s[a] = 0.0f;
    #pragma unroll
    for (int b = 0; b < 8; ++b) {
      const int j = tj * 8 + b;
      const int swj = ((j >> 2) & 15) << 2;
      float dv[8];
      *reinterpret_cast<float4*>(&dv[0]) =
          *reinterpret_cast<const float4*>(&XT[j][(tn * 8) ^ swj]);
      *reinterpret_cast<float4*>(&dv[4]) =
          *reinterpret_cast<const float4*>(&XT[j][(tn * 8 + 4) ^ swj]);
      const float mj = muw[0][j];
      const float wj = muw[1][j];
      #pragma unroll
      for (int a = 0; a < 8; ++a)
        s[a] = fmaf(dv[a] - mj, y[a][b] - wj, s[a]);
    }

    float* qred = &Pw[0][0][0][0];  // 2048 floats needed; Pw (2176) dead now
    *reinterpret_cast<float4*>(&qred[tj * 64 + tn * 8]) =
        *reinterpret_cast<const float4*>(&s[0]);
    *reinterpret_cast<float4*>(&qred[tj * 64 + tn * 8 + 4]) =
        *reinterpret_cast<const float4*>(&s[4]);
    __syncthreads();
    if (tid < 64) {
      float qa = 0.f, qb = 0.f, qc = 0.f, qd = 0.f;
      #pragma unroll
      for (int t = 0; t < 32; t += 4) {
        qa += qred[(t + 0) * 64 + tid];
        qb += qred[(t + 1) * 64 + tid];
        qc += qred[(t + 2) * 64 + tid];
        qd += qred[(t + 3) * 64 + tid];
      }
      // q' = dev^T S dev = -quad  ->  lp = cA + 0.5*q'
      lpb[kk][tid] = fmaf(0.5f, (qa + qb) + (qc + qd), cA[k]);
    }
  }

  // lp flush: one float4 of 4 k-values per point row
  __syncthreads();
  if (tid < 64) {
    float4 o = {lpb[0][tid], lpb[1][tid], lpb[2][tid], lpb[3][tid]};
    *reinterpret_cast<float4*>(&lp[(size_t)(n0 + tid) * KC + k0]) = o;
  }
}

// ---------------- Kernel 3: row softmax over K+1 = 65 entries -----------------
__global__ __launch_bounds__(64) void softmax_kernel(
    const float* __restrict__ lp, const int* __restrict__ n_points_p,
    float* __restrict__ out)
{
  const int n = blockIdx.x;
  const int l = threadIdx.x;
  const float denom = (float)(*n_points_p) + 1.0f;
  const float log_new = -logf(denom);  // log(ALPHA/denom), ALPHA=1

  float v = lp[(size_t)n * KC + l];
  float m = v;
  #pragma unroll
  for (int off = 32; off > 0; off >>= 1) m = fmaxf(m, __shfl_xor(m, off, 64));
  m = fmaxf(m, log_new);

  float e = expf(v - m);
  float s = e;
  #pragma unroll
  for (int off = 32; off > 0; off >>= 1) s += __shfl_xor(s, off, 64);
  float enew = expf(log_new - m);
  s += enew;

  out[(size_t)n * (KC + 1) + l] = e / s;
  if (l == 0) out[(size_t)n * (KC + 1) + KC] = enew / s;
}

extern "C" void kernel_launch(void* const* d_in, const int* in_sizes, int n_in,
                              void* d_out, int out_size, void* d_ws, size_t ws_size,
                              hipStream_t stream)
{
  const float* x       = (const float*)d_in[0];  // [N, D]
  const float* means   = (const float*)d_in[1];  // [K, D]
  const float* covs    = (const float*)d_in[2];  // [K, D, D]
  const float* counts  = (const float*)d_in[3];  // [K]
  const int*   n_points = (const int*)d_in[4];   // scalar

  float* S   = (float*)d_ws;                      // K*D*D
  float* cA  = S + (size_t)KC * DD * DD;          // K
  float* ldp = cA + KC;                           // 4*K
  float* lp  = ldp + 4 * KC;                      // N*K
  float* out = (float*)d_out;                     // [N, K+1]
  // wv = S_k*mu_k staged in the out buffer (64KB of 1MB); quad reads it before
  // softmax overwrites out — stream-ordered, safe.
  float* wv = out;

  init_kernel<<<KC, 512, 0, stream>>>(covs, S, ldp);
  for (int bs = 0; bs < 4; ++bs)
    step_kernel<<<dim3(KC, 3), 512, 0, stream>>>(covs, S, ldp, bs);
  final_kernel<<<KC, 512, 0, stream>>>(S, means, counts, n_points, ldp, cA, wv);
  quad_kernel<<<dim3(NPTS / NT, KC / KG), 256, 0, stream>>>(x, means, S, cA, wv, lp);
  softmax_kernel<<<NPTS, 64, 0, stream>>>(lp, n_points, out);
}

// Round 15
// 648.754 us; speedup vs baseline: 1.1459x; 1.1459x over previous
//
#include <hip/hip_runtime.h>
#include <math.h>

// StreamingDPM: probs = softmax([ -0.5*(D log2pi + logdet_k + quad_nk) + log_prior_k | log_new ])
// N=4096 D=256 K=64, out [N, K+1] fp32.
//
// ws layout (floats):
//   S    : K*D*D  (sweep result; holds -Sigma^{-1} after all steps)
//   cA   : K      (log_prior_k - 0.5*(D log2pi + logdet_k))
//   ldp  : 4*K    (per-block-step logdet partials)
//   lp   : N*K    (log-probs before softmax; ALIASED as Plbuf during sweep)
// wv (= S_k * mu_k, [K][D]) lives in the OUTPUT buffer temporarily (quad reads
// it before softmax overwrites out; stream-ordered, safe).
//
// Sweep: r11's proven multi-launch chain (211us). Tried and rejected:
//   - cooperative single-kernel (r9): grid.sync ~70us each -> 687us.
//   - 7-launch fused step kernels (r14): defer path spills (~130 live floats)
//     -> chain 327us, WORSE than the launch overhead it saved.

#define DD 256
#define KC 64
#define NPTS 4096
#define NT 64
#define BB 64          // sweep block size
#define KG 4           // clusters per quad block

// ---------------- Kernel 1a: pivot sweep + deferred J-col writeback ----------
__global__ __launch_bounds__(512) void pivot_kernel(
    const float* __restrict__ covs, float* __restrict__ S,
    float* __restrict__ Plbuf, float* __restrict__ ldp, int bs)
{
  const int k = blockIdx.x;
  const int by = blockIdx.y;
  const int tid = threadIdx.x;
  float* Pb = Plbuf + (size_t)k * BB * BB;

  __shared__ __align__(16) float Tl[BB][BB + 4];
  __shared__ __align__(16) float pivc[2][BB];
  __shared__ __align__(16) float pivr[2][BB];

  if (by < 4) {
    // ---- deferred write of step bs-1's J columns (rows r0..r0+63):
    //  M[J,J] = -P^{-1} = Pb ;  M[I,J] = C*P^{-1} = -(C*Pb)
    if (bs == 0) return;
    const int j0p = (bs - 1) * BB;
    const int r0 = by * BB;
    const float* src = ((bs == 1) ? covs : (const float*)S) + (size_t)k * DD * DD;
    float* dst = S + (size_t)k * DD * DD;

    const int rr = tid >> 3;         // 0..63
    const int cc = (tid & 7) * 8;    // 0..56
    *reinterpret_cast<float4*>(&Tl[rr][cc]) =
        *reinterpret_cast<const float4*>(&Pb[rr * BB + cc]);
    *reinterpret_cast<float4*>(&Tl[rr][cc + 4]) =
        *reinterpret_cast<const float4*>(&Pb[rr * BB + cc + 4]);
    __syncthreads();

    const int r = r0 + rr;
    if (r0 == j0p) {
      // rows in J: direct copy of -P^{-1}
      *reinterpret_cast<float4*>(&dst[(size_t)r * DD + j0p + cc]) =
          *reinterpret_cast<const float4*>(&Tl[rr][cc]);
      *reinterpret_cast<float4*>(&dst[(size_t)r * DD + j0p + cc + 4]) =
          *reinterpret_cast<const float4*>(&Tl[rr][cc + 4]);
    } else {
      float Crow[BB];
      #pragma unroll
      for (int p = 0; p < BB; p += 4) {
        float4 cv = *reinterpret_cast<const float4*>(&src[(size_t)r * DD + j0p + p]);
        Crow[p] = cv.x; Crow[p + 1] = cv.y; Crow[p + 2] = cv.z; Crow[p + 3] = cv.w;
      }
      float acc[8] = {0.f, 0.f, 0.f, 0.f, 0.f, 0.f, 0.f, 0.f};
      #pragma unroll
      for (int p = 0; p < BB; ++p) {
        float4 t0 = *reinterpret_cast<const float4*>(&Tl[p][cc]);
        float4 t1 = *reinterpret_cast<const float4*>(&Tl[p][cc + 4]);
        acc[0] = fmaf(Crow[p], t0.x, acc[0]);
        acc[1] = fmaf(Crow[p], t0.y, acc[1]);
        acc[2] = fmaf(Crow[p], t0.z, acc[2]);
        acc[3] = fmaf(Crow[p], t0.w, acc[3]);
        acc[4] = fmaf(Crow[p], t1.x, acc[4]);
        acc[5] = fmaf(Crow[p], t1.y, acc[5]);
        acc[6] = fmaf(Crow[p], t1.z, acc[6]);
        acc[7] = fmaf(Crow[p], t1.w, acc[7]);
      }
      float4 o0 = {-acc[0], -acc[1], -acc[2], -acc[3]};
      float4 o1 = {-acc[4], -acc[5], -acc[6], -acc[7]};
      *reinterpret_cast<float4*>(&dst[(size_t)r * DD + j0p + cc]) = o0;
      *reinterpret_cast<float4*>(&dst[(size_t)r * DD + j0p + cc + 4]) = o1;
    }
    return;
  }

  if (bs == 4) return;  // flush launch: defer blocks only

  // ---- register-resident sweep of P = S[J,J] (step 0: from covs).
  // Thread owns row pr, cols pc..pc+7 in VGPRs for all 64 pivots; only the
  // pivot row/col is exchanged via double-buffered LDS. 1 barrier per pivot.
  const int j0 = bs * BB;
  const float* psrc = ((bs == 0) ? covs : (const float*)S) + (size_t)k * DD * DD;
  const int pr = tid >> 3;
  const int pc = (tid & 7) * 8;

  float v[8];
  {
    float4 a4 = *reinterpret_cast<const float4*>(&psrc[(size_t)(j0 + pr) * DD + j0 + pc]);
    float4 b4 = *reinterpret_cast<const float4*>(&psrc[(size_t)(j0 + pr) * DD + j0 + pc + 4]);
    v[0] = a4.x; v[1] = a4.y; v[2] = a4.z; v[3] = a4.w;
    v[4] = b4.x; v[5] = b4.y; v[6] = b4.z; v[7] = b4.w;
  }
  if (pc == 0) pivc[0][pr] = v[0];
  if (pr == 0) {
    #pragma unroll
    for (int e = 0; e < 8; ++e) pivr[0][pc + e] = v[e];
  }
  __syncthreads();

  float ld = 0.0f;
  #pragma unroll 1
  for (int p = 0; p < BB; ++p) {
    const int cur = p & 1, nxt = cur ^ 1;
    const float d = pivc[cur][p];
    const float inv_d = 1.0f / d;
    if (tid == 0) ld += logf(d);
    const float cr = pivc[cur][pr];
    float rw[8];
    *reinterpret_cast<float4*>(&rw[0]) = *reinterpret_cast<const float4*>(&pivr[cur][pc]);
    *reinterpret_cast<float4*>(&rw[4]) = *reinterpret_cast<const float4*>(&pivr[cur][pc + 4]);
    #pragma unroll
    for (int e = 0; e < 8; ++e) {
      float ge = fmaf(-inv_d * cr, rw[e], v[e]);         // general update
      if (pr == p)     ge = rw[e] * inv_d;               // pivot row
      if (pc + e == p) ge = (pr == p) ? -inv_d : cr * inv_d;  // pivot col/diag
      v[e] = ge;
    }
    if (p < BB - 1) {
      if (pr == p + 1) {
        #pragma unroll
        for (int e = 0; e < 8; ++e) pivr[nxt][pc + e] = v[e];
      }
      if (pc <= p + 1 && p + 1 < pc + 8) pivc[nxt][pr] = v[p + 1 - pc];
    }
    __syncthreads();
  }

  // store -P^{-1} for the update/deferred kernels (coalesced)
  float4 s0 = {v[0], v[1], v[2], v[3]};
  float4 s1 = {v[4], v[5], v[6], v[7]};
  *reinterpret_cast<float4*>(&Pb[pr * BB + pc]) = s0;
  *reinterpret_cast<float4*>(&Pb[pr * BB + pc + 4]) = s1;
  if (tid == 0) ldp[bs * KC + k] = ld;
}

// ---------------- Kernel 1b: trailing update of one non-J column slice ------
__global__ __launch_bounds__(512) void update_kernel(
    const float* __restrict__ covs, float* __restrict__ S,
    const float* __restrict__ Plbuf, int bs)
{
  const int k = blockIdx.x;
  const int si = blockIdx.y;
  const int t = si + (si >= bs ? 1 : 0);
  const int c0 = t * BB;
  const int j0 = bs * BB;
  const int tid = threadIdx.x;
  const float* src = ((bs == 0) ? covs : (const float*)S) + (size_t)k * DD * DD;
  float* dst = S + (size_t)k * DD * DD;

  __shared__ __align__(16) float Pl[BB][BB + 4];
  __shared__ __align__(16) float SJ[BB][BB + 4];
  __shared__ __align__(16) float Tl[BB][BB + 4];

  const float* Pb = Plbuf + (size_t)k * BB * BB;
  #pragma unroll
  for (int q = 0; q < 8; ++q) {
    int e = q * 512 + tid;
    int r = e >> 6, c = e & 63;
    Pl[r][c] = Pb[e];
    SJ[r][c] = src[(size_t)(j0 + r) * DD + c0 + c];
  }
  __syncthreads();

  // ---- T' = Pl * SJ  (thread: col c, 8 rows)
  {
    const int c = tid & 63;
    const int rg = (tid >> 6) * 8;
    float tv[8];
    #pragma unroll
    for (int r = 0; r < 8; ++r) tv[r] = 0.0f;
    for (int p = 0; p < BB; p += 4) {
      float s0 = SJ[p][c], s1 = SJ[p + 1][c], s2 = SJ[p + 2][c], s3 = SJ[p + 3][c];
      #pragma unroll
      for (int r = 0; r < 8; ++r) {
        float4 pv = *reinterpret_cast<const float4*>(&Pl[rg + r][p]);
        tv[r] = fmaf(pv.x, s0, fmaf(pv.y, s1, fmaf(pv.z, s2, fmaf(pv.w, s3, tv[r]))));
      }
    }
    #pragma unroll
    for (int r = 0; r < 8; ++r) Tl[rg + r][c] = tv[r];
  }
  __syncthreads();

  // ---- apply to this column slice (thread: row r, 32 cols)
  const int r = tid & 255;
  const int h = (tid >> 8) * 32;
  const bool inJ = (r >= j0) && (r < j0 + BB);  // wave-uniform
  if (inJ) {
    #pragma unroll
    for (int c = 0; c < 32; c += 4) {
      float4 tv4 = *reinterpret_cast<const float4*>(&Tl[r - j0][h + c]);
      float4 o = {-tv4.x, -tv4.y, -tv4.z, -tv4.w};
      *reinterpret_cast<float4*>(&dst[(size_t)r * DD + c0 + h + c]) = o;
    }
  } else {
    float Crow[BB];
    #pragma unroll
    for (int p = 0; p < BB; p += 4) {
      float4 cv = *reinterpret_cast<const float4*>(&src[(size_t)r * DD + j0 + p]);
      Crow[p] = cv.x; Crow[p + 1] = cv.y; Crow[p + 2] = cv.z; Crow[p + 3] = cv.w;
    }
    #pragma unroll
    for (int c = 0; c < 32; c += 4) {
      float4 acc = *reinterpret_cast<const float4*>(&src[(size_t)r * DD + c0 + h + c]);
      #pragma unroll
      for (int p = 0; p < BB; ++p) {
        float4 tv4 = *reinterpret_cast<const float4*>(&Tl[p][h + c]);
        acc.x = fmaf(Crow[p], tv4.x, acc.x);
        acc.y = fmaf(Crow[p], tv4.y, acc.y);
        acc.z = fmaf(Crow[p], tv4.z, acc.z);
        acc.w = fmaf(Crow[p], tv4.w, acc.w);
      }
      *reinterpret_cast<float4*>(&dst[(size_t)r * DD + c0 + h + c]) = acc;
    }
  }
}

// ---------------- Kernel 1c: wv_k = S_k * mu_k ; cA assembly -----------------
__global__ __launch_bounds__(256) void w_kernel(
    const float* __restrict__ S, const float* __restrict__ means,
    const float* __restrict__ counts, const int* __restrict__ n_points_p,
    const float* __restrict__ ldp, float* __restrict__ cA,
    float* __restrict__ wv)
{
  const int k = blockIdx.x;
  const int tid = threadIdx.x;
  if (tid == 0) {
    float denom = (float)(*n_points_p) + 1.0f;  // ALPHA = 1
    float ld = ldp[k] + ldp[KC + k] + ldp[2 * KC + k] + ldp[3 * KC + k];
    // D*log(2*pi) = 256 * 1.8378770664093453
    cA[k] = logf(counts[k] / denom) - 0.5f * (470.49652900079047f + ld);
  }
  const float* Sk = S + (size_t)k * DD * DD;
  __shared__ float mus[DD];
  mus[tid] = means[(size_t)k * DD + tid];
  __syncthreads();
  float a0 = 0.f, a1 = 0.f, a2 = 0.f, a3 = 0.f;
  for (int j = 0; j < DD; j += 4) {
    a0 = fmaf(Sk[(size_t)(j + 0) * DD + tid], mus[j + 0], a0);
    a1 = fmaf(Sk[(size_t)(j + 1) * DD + tid], mus[j + 1], a1);
    a2 = fmaf(Sk[(size_t)(j + 2) * DD + tid], mus[j + 2], a2);
    a3 = fmaf(Sk[(size_t)(j + 3) * DD + tid], mus[j + 3], a3);
  }
  wv[(size_t)k * DD + tid] = (a0 + a1) + (a2 + a3);
}

// ---------------- Kernel 2: quad, wave-private strips + 1-il-ahead pipeline --
// dev^T S dev = sum_j (x_j - mu_j) * ((X*S)_nj - wv_j)   (S symmetric).
// r11 structure (407us, 74% VALU): wave-private double-buffered S strips,
// zero inner barriers. NEW: explicit one-il-ahead software pipeline -- named
// double-buffers xvA/xvB (XT reads) and pvA/pvB (strip reads), each loaded one
// il before its FMA block, chunk-publish moved to the START of the ct body so
// il=3 can prefetch the next chunk's pv (LDS ops are in-order per wave).
// Targets the 26% VALU idle (lgkmcnt waits on load->FMA). ~112 live VGPR.
__global__ __launch_bounds__(256) void quad_kernel(
    const float* __restrict__ X, const float* __restrict__ means,
    const float* __restrict__ S, const float* __restrict__ cA,
    const float* __restrict__ wv, float* __restrict__ lp)
{
  __shared__ __align__(16) float XT[DD][NT];        // (i,r) at XT[i][r ^ (((i>>2)&15)<<2)]
  __shared__ __align__(16) float Pw[4][2][4][68];   // wave-private S strips; qred alias
  __shared__ __align__(16) float muw[2][DD];        // mu_k, wv_k
  __shared__ __align__(16) float lpb[KG][NT];       // results, flushed at end

  const int tid = threadIdx.x;
  const int n0 = blockIdx.x * NT;
  const int k0 = blockIdx.y * KG;

  // stage X tile transposed + swizzled (once per block)
  #pragma unroll
  for (int q = 0; q < 16; ++q) {
    int f = q * 1024 + tid * 4;
    int r = f >> 8;
    int c = f & 255;
    float4 xv = *reinterpret_cast<const float4*>(X + (size_t)(n0 + r) * DD + c);
    int rs = r ^ (((c >> 2) & 15) << 2);
    XT[c + 0][rs] = xv.x;
    XT[c + 1][rs] = xv.y;
    XT[c + 2][rs] = xv.z;
    XT[c + 3][rs] = xv.w;
  }

  const int tn = tid & 7;          // n sub-tile: rows tn*8 .. +7
  const int tj = tid >> 3;         // j sub-tile: cols tj*8 .. +7
  const int wid = tid >> 6;        // wave id 0..3
  const int lane = tid & 63;
  const int g = (tid >> 3) & 7;    // tj within wave
  const int srow = lane >> 4;      // staging row within 4-row chunk
  const int scol = (lane & 15) * 4;// staging col (float4)

  #pragma unroll 1
  for (int kk = 0; kk < KG; ++kk) {
    const int k = k0 + kk;
    const float* Skw = S + (size_t)k * DD * DD + wid * 64;  // wave's col slice

    __syncthreads();  // prev k's qred readers done (Pw aliased); XT staged
    muw[0][tid] = means[(size_t)k * DD + tid];
    muw[1][tid] = wv[(size_t)k * DD + tid];

    // prologue: chunk 0 -> LDS buf 0; chunk 1 -> st regs
    float4 st = *reinterpret_cast<const float4*>(Skw + (size_t)srow * DD + scol);
    *reinterpret_cast<float4*>(&Pw[wid][0][srow][scol]) = st;
    st = *reinterpret_cast<const float4*>(Skw + (size_t)(4 + srow) * DD + scol);

    float y[8][8];
    #pragma unroll
    for (int a = 0; a < 8; ++a)
      #pragma unroll
      for (int b = 0; b < 8; ++b) y[a][b] = 0.0f;

    // pipeline prologue: xv(i=0) and pv(chunk0,row0)
    float xvA[8], xvB[8], pvA[8], pvB[8];
    *reinterpret_cast<float4*>(&xvA[0]) =
        *reinterpret_cast<const float4*>(&XT[0][(tn * 8) ^ 0]);
    *reinterpret_cast<float4*>(&xvA[4]) =
        *reinterpret_cast<const float4*>(&XT[0][(tn * 8 + 4) ^ 0]);
    *reinterpret_cast<float4*>(&pvA[0]) =
        *reinterpret_cast<const float4*>(&Pw[wid][0][0][g * 8]);
    *reinterpret_cast<float4*>(&pvA[4]) =
        *reinterpret_cast<const float4*>(&Pw[wid][0][0][g * 8 + 4]);

    #pragma unroll 1
    for (int ct = 0; ct < 64; ++ct) {
      const int cur = ct & 1;
      // publish chunk ct+1 FIRST (into the non-current buffer) so il=3's pv
      // prefetch can target it; wave-private + in-order LDS -> no barrier.
      if (ct < 63)
        *reinterpret_cast<float4*>(&Pw[wid][cur ^ 1][srow][scol]) = st;

      #pragma unroll
      for (int il = 0; il < 4; ++il) {
        const int i = ct * 4 + il;
        // prefetch next il's xv into the other buffer (static parity)
        {
          const int inx = (i + 1 < DD) ? (i + 1) : (DD - 1);
          const int swn = ((inx >> 2) & 15) << 2;
          if ((il & 1) == 0) {
            *reinterpret_cast<float4*>(&xvB[0]) =
                *reinterpret_cast<const float4*>(&XT[inx][(tn * 8) ^ swn]);
            *reinterpret_cast<float4*>(&xvB[4]) =
                *reinterpret_cast<const float4*>(&XT[inx][(tn * 8 + 4) ^ swn]);
          } else {
            *reinterpret_cast<float4*>(&xvA[0]) =
                *reinterpret_cast<const float4*>(&XT[inx][(tn * 8) ^ swn]);
            *reinterpret_cast<float4*>(&xvA[4]) =
                *reinterpret_cast<const float4*>(&XT[inx][(tn * 8 + 4) ^ swn]);
          }
        }
        // prefetch next il's pv (il==3 -> row 0 of the next chunk, published above)
        {
          const int nb = (il == 3) ? (cur ^ 1) : cur;
          const int nr = (il == 3) ? 0 : (il + 1);
          if ((il & 1) == 0) {
            *reinterpret_cast<float4*>(&pvB[0]) =
                *reinterpret_cast<const float4*>(&Pw[wid][nb][nr][g * 8]);
            *reinterpret_cast<float4*>(&pvB[4]) =
                *reinterpret_cast<const float4*>(&Pw[wid][nb][nr][g * 8 + 4]);
          } else {
            *reinterpret_cast<float4*>(&pvA[0]) =
                *reinterpret_cast<const float4*>(&Pw[wid][nb][nr][g * 8]);
            *reinterpret_cast<float4*>(&pvA[4]) =
                *reinterpret_cast<const float4*>(&Pw[wid][nb][nr][g * 8 + 4]);
          }
        }
        // FMA block on the current (already-loaded) buffers
        if ((il & 1) == 0) {
          #pragma unroll
          for (int a = 0; a < 8; ++a)
            #pragma unroll
            for (int b = 0; b < 8; ++b)
              y[a][b] = fmaf(xvA[a], pvA[b], y[a][b]);
        } else {
          #pragma unroll
          for (int a = 0; a < 8; ++a)
            #pragma unroll
            for (int b = 0; b < 8; ++b)
              y[a][b] = fmaf(xvB[a], pvB[b], y[a][b]);
        }
      }
      if (ct < 63) {
        // prefetch chunk ct+2 from global (in flight across next ct body)
        const int cnx = (ct + 2 < 64) ? (ct + 2) : 63;
        st = *reinterpret_cast<const float4*>(
            Skw + (size_t)(cnx * 4 + srow) * DD + scol);
      }
    }
    __syncthreads();  // muw visible; all waves done with Pw before qred reuse

    // epilogue: q'[n] = sum_j (x[n,j]-mu_j) * (y[n,j]-wv_j), partial over 8 j
    float s[8];
    #pragma unroll
    for (int a = 0; a < 8; ++a) s[a] = 0.0f;
    #pragma unroll
    for (int b = 0; b < 8; ++b) {
      const int j = tj * 8 + b;
      const int swj = ((j >> 2) & 15) << 2;
      float dv[8];
      *reinterpret_cast<float4*>(&dv[0]) =
          *reinterpret_cast<const float4*>(&XT[j][(tn * 8) ^ swj]);
      *reinterpret_cast<float4*>(&dv[4]) =
          *reinterpret_cast<const float4*>(&XT[j][(tn * 8 + 4) ^ swj]);
      const float mj = muw[0][j];
      const float wj = muw[1][j];
      #pragma unroll
      for (int a = 0; a < 8; ++a)
        s[a] = fmaf(dv[a] - mj, y[a][b] - wj, s[a]);
    }

    float* qred = &Pw[0][0][0][0];  // 2048 floats needed; Pw (2176) dead now
    *reinterpret_cast<float4*>(&qred[tj * 64 + tn * 8]) =
        *reinterpret_cast<const float4*>(&s[0]);
    *reinterpret_cast<float4*>(&qred[tj * 64 + tn * 8 + 4]) =
        *reinterpret_cast<const float4*>(&s[4]);
    __syncthreads();
    if (tid < 64) {
      float qa = 0.f, qb = 0.f, qc = 0.f, qd = 0.f;
      #pragma unroll
      for (int t = 0; t < 32; t += 4) {
        qa += qred[(t + 0) * 64 + tid];
        qb += qred[(t + 1) * 64 + tid];
        qc += qred[(t + 2) * 64 + tid];
        qd += qred[(t + 3) * 64 + tid];
      }
      // q' = dev^T S dev = -quad  ->  lp = cA + 0.5*q'
      lpb[kk][tid] = fmaf(0.5f, (qa + qb) + (qc + qd), cA[k]);
    }
  }

  // lp flush: one float4 of 4 k-values per point row
  __syncthreads();
  if (tid < 64) {
    float4 o = {lpb[0][tid], lpb[1][tid], lpb[2][tid], lpb[3][tid]};
    *reinterpret_cast<float4*>(&lp[(size_t)(n0 + tid) * KC + k0]) = o;
  }
}

// ---------------- Kernel 3: row softmax over K+1 = 65 entries -----------------
__global__ __launch_bounds__(64) void softmax_kernel(
    const float* __restrict__ lp, const int* __restrict__ n_points_p,
    float* __restrict__ out)
{
  const int n = blockIdx.x;
  const int l = threadIdx.x;
  const float denom = (float)(*n_points_p) + 1.0f;
  const float log_new = -logf(denom);  // log(ALPHA/denom), ALPHA=1

  float v = lp[(size_t)n * KC + l];
  float m = v;
  #pragma unroll
  for (int off = 32; off > 0; off >>= 1) m = fmaxf(m, __shfl_xor(m, off, 64));
  m = fmaxf(m, log_new);

  float e = expf(v - m);
  float s = e;
  #pragma unroll
  for (int off = 32; off > 0; off >>= 1) s += __shfl_xor(s, off, 64);
  float enew = expf(log_new - m);
  s += enew;

  out[(size_t)n * (KC + 1) + l] = e / s;
  if (l == 0) out[(size_t)n * (KC + 1) + KC] = enew / s;
}

extern "C" void kernel_launch(void* const* d_in, const int* in_sizes, int n_in,
                              void* d_out, int out_size, void* d_ws, size_t ws_size,
                              hipStream_t stream)
{
  const float* x       = (const float*)d_in[0];  // [N, D]
  const float* means   = (const float*)d_in[1];  // [K, D]
  const float* covs    = (const float*)d_in[2];  // [K, D, D]
  const float* counts  = (const float*)d_in[3];  // [K]
  const int*   n_points = (const int*)d_in[4];   // scalar

  float* S   = (float*)d_ws;                      // K*D*D
  float* cA  = S + (size_t)KC * DD * DD;          // K
  float* ldp = cA + KC;                           // 4*K
  float* lp  = ldp + 4 * KC;                      // N*K
  float* Plbuf = lp;  // alias: Plbuf (K*64*64 = N*K floats) used only during
                      // sweep; lp written only by quad afterwards.
  float* out = (float*)d_out;                     // [N, K+1]
  // wv = S_k*mu_k staged in the out buffer (64KB of 1MB); quad reads it before
  // softmax overwrites out — stream-ordered, safe.
  float* wv = out;

  for (int bs = 0; bs < 4; ++bs) {
    pivot_kernel<<<dim3(KC, 5), 512, 0, stream>>>(covs, S, Plbuf, ldp, bs);
    update_kernel<<<dim3(KC, 3), 512, 0, stream>>>(covs, S, Plbuf, bs);
  }
  pivot_kernel<<<dim3(KC, 5), 512, 0, stream>>>(covs, S, Plbuf, ldp, 4);
  w_kernel<<<KC, 256, 0, stream>>>(S, means, counts, n_points, ldp, cA, wv);
  quad_kernel<<<dim3(NPTS / NT, KC / KG), 256, 0, stream>>>(x, means, S, cA, wv, lp);
  softmax_kernel<<<NPTS, 64, 0, stream>>>(lp, n_points, out);
}

// Round 16
// 637.417 us; speedup vs baseline: 1.1662x; 1.0178x over previous
//
#include <hip/hip_runtime.h>
#include <math.h>

// StreamingDPM: probs = softmax([ -0.5*(D log2pi + logdet_k + quad_nk) + log_prior_k | log_new ])
// N=4096 D=256 K=64, out [N, K+1] fp32.
//
// ws layout (floats):
//   S    : K*D*D  (sweep result; holds -Sigma^{-1} after all steps)
//   cA   : K      (log_prior_k - 0.5*(D log2pi + logdet_k))
//   ldp  : 4*K    (per-block-step logdet partials)
//   lp   : N*K    (log-probs before softmax; ALIASED as Plbuf during sweep)
// wv (= S_k * mu_k, [K][D]) lives in the OUTPUT buffer temporarily (quad reads
// it before softmax overwrites out; stream-ordered, safe).
//
// Sweep: r11's proven multi-launch chain, with the final flush fused:
//   pivot(bs) x4  : defer J-cols of bs-1 (4 parallel blocks) + sweep P_bs.
//   update(bs) x4 : trailing update of the 3 non-J column slices.
//   final_kernel  : J3 defer (from Plbuf; values kept in LDS) + wv + cA.
// Rejected by measurement: cooperative fusion (r9, grid.sync ~70us), deep
// step fusion (r14, defer-path spill), manual quad SW pipeline (r15, +34us).

#define DD 256
#define KC 64
#define NPTS 4096
#define NT 64
#define BB 64          // sweep block size
#define KG 8           // clusters per quad block (512 blocks = exactly 2/CU)

// ---------------- Kernel 1a: pivot sweep + deferred J-col writeback ----------
__global__ __launch_bounds__(512) void pivot_kernel(
    const float* __restrict__ covs, float* __restrict__ S,
    float* __restrict__ Plbuf, float* __restrict__ ldp, int bs)
{
  const int k = blockIdx.x;
  const int by = blockIdx.y;
  const int tid = threadIdx.x;
  float* Pb = Plbuf + (size_t)k * BB * BB;

  __shared__ __align__(16) float Tl[BB][BB + 4];
  __shared__ __align__(16) float pivc[2][BB];
  __shared__ __align__(16) float pivr[2][BB];

  if (by < 4) {
    // ---- deferred write of step bs-1's J columns (rows r0..r0+63):
    //  M[J,J] = -P^{-1} = Pb ;  M[I,J] = C*P^{-1} = -(C*Pb)
    if (bs == 0) return;
    const int j0p = (bs - 1) * BB;
    const int r0 = by * BB;
    const float* src = ((bs == 1) ? covs : (const float*)S) + (size_t)k * DD * DD;
    float* dst = S + (size_t)k * DD * DD;

    const int rr = tid >> 3;         // 0..63
    const int cc = (tid & 7) * 8;    // 0..56
    *reinterpret_cast<float4*>(&Tl[rr][cc]) =
        *reinterpret_cast<const float4*>(&Pb[rr * BB + cc]);
    *reinterpret_cast<float4*>(&Tl[rr][cc + 4]) =
        *reinterpret_cast<const float4*>(&Pb[rr * BB + cc + 4]);
    __syncthreads();

    const int r = r0 + rr;
    if (r0 == j0p) {
      // rows in J: direct copy of -P^{-1}
      *reinterpret_cast<float4*>(&dst[(size_t)r * DD + j0p + cc]) =
          *reinterpret_cast<const float4*>(&Tl[rr][cc]);
      *reinterpret_cast<float4*>(&dst[(size_t)r * DD + j0p + cc + 4]) =
          *reinterpret_cast<const float4*>(&Tl[rr][cc + 4]);
    } else {
      float Crow[BB];
      #pragma unroll
      for (int p = 0; p < BB; p += 4) {
        float4 cv = *reinterpret_cast<const float4*>(&src[(size_t)r * DD + j0p + p]);
        Crow[p] = cv.x; Crow[p + 1] = cv.y; Crow[p + 2] = cv.z; Crow[p + 3] = cv.w;
      }
      float acc[8] = {0.f, 0.f, 0.f, 0.f, 0.f, 0.f, 0.f, 0.f};
      #pragma unroll
      for (int p = 0; p < BB; ++p) {
        float4 t0 = *reinterpret_cast<const float4*>(&Tl[p][cc]);
        float4 t1 = *reinterpret_cast<const float4*>(&Tl[p][cc + 4]);
        acc[0] = fmaf(Crow[p], t0.x, acc[0]);
        acc[1] = fmaf(Crow[p], t0.y, acc[1]);
        acc[2] = fmaf(Crow[p], t0.z, acc[2]);
        acc[3] = fmaf(Crow[p], t0.w, acc[3]);
        acc[4] = fmaf(Crow[p], t1.x, acc[4]);
        acc[5] = fmaf(Crow[p], t1.y, acc[5]);
        acc[6] = fmaf(Crow[p], t1.z, acc[6]);
        acc[7] = fmaf(Crow[p], t1.w, acc[7]);
      }
      float4 o0 = {-acc[0], -acc[1], -acc[2], -acc[3]};
      float4 o1 = {-acc[4], -acc[5], -acc[6], -acc[7]};
      *reinterpret_cast<float4*>(&dst[(size_t)r * DD + j0p + cc]) = o0;
      *reinterpret_cast<float4*>(&dst[(size_t)r * DD + j0p + cc + 4]) = o1;
    }
    return;
  }

  // ---- register-resident sweep of P = S[J,J] (step 0: from covs).
  // Thread owns row pr, cols pc..pc+7 in VGPRs for all 64 pivots; only the
  // pivot row/col is exchanged via double-buffered LDS. 1 barrier per pivot.
  const int j0 = bs * BB;
  const float* psrc = ((bs == 0) ? covs : (const float*)S) + (size_t)k * DD * DD;
  const int pr = tid >> 3;
  const int pc = (tid & 7) * 8;

  float v[8];
  {
    float4 a4 = *reinterpret_cast<const float4*>(&psrc[(size_t)(j0 + pr) * DD + j0 + pc]);
    float4 b4 = *reinterpret_cast<const float4*>(&psrc[(size_t)(j0 + pr) * DD + j0 + pc + 4]);
    v[0] = a4.x; v[1] = a4.y; v[2] = a4.z; v[3] = a4.w;
    v[4] = b4.x; v[5] = b4.y; v[6] = b4.z; v[7] = b4.w;
  }
  if (pc == 0) pivc[0][pr] = v[0];
  if (pr == 0) {
    #pragma unroll
    for (int e = 0; e < 8; ++e) pivr[0][pc + e] = v[e];
  }
  __syncthreads();

  float ld = 0.0f;
  #pragma unroll 1
  for (int p = 0; p < BB; ++p) {
    const int cur = p & 1, nxt = cur ^ 1;
    const float d = pivc[cur][p];
    const float inv_d = 1.0f / d;
    if (tid == 0) ld += logf(d);
    const float cr = pivc[cur][pr];
    float rw[8];
    *reinterpret_cast<float4*>(&rw[0]) = *reinterpret_cast<const float4*>(&pivr[cur][pc]);
    *reinterpret_cast<float4*>(&rw[4]) = *reinterpret_cast<const float4*>(&pivr[cur][pc + 4]);
    #pragma unroll
    for (int e = 0; e < 8; ++e) {
      float ge = fmaf(-inv_d * cr, rw[e], v[e]);         // general update
      if (pr == p)     ge = rw[e] * inv_d;               // pivot row
      if (pc + e == p) ge = (pr == p) ? -inv_d : cr * inv_d;  // pivot col/diag
      v[e] = ge;
    }
    if (p < BB - 1) {
      if (pr == p + 1) {
        #pragma unroll
        for (int e = 0; e < 8; ++e) pivr[nxt][pc + e] = v[e];
      }
      if (pc <= p + 1 && p + 1 < pc + 8) pivc[nxt][pr] = v[p + 1 - pc];
    }
    __syncthreads();
  }

  // store -P^{-1} for the update/deferred kernels (coalesced)
  float4 s0 = {v[0], v[1], v[2], v[3]};
  float4 s1 = {v[4], v[5], v[6], v[7]};
  *reinterpret_cast<float4*>(&Pb[pr * BB + pc]) = s0;
  *reinterpret_cast<float4*>(&Pb[pr * BB + pc + 4]) = s1;
  if (tid == 0) ldp[bs * KC + k] = ld;
}

// ---------------- Kernel 1b: trailing update of one non-J column slice ------
__global__ __launch_bounds__(512) void update_kernel(
    const float* __restrict__ covs, float* __restrict__ S,
    const float* __restrict__ Plbuf, int bs)
{
  const int k = blockIdx.x;
  const int si = blockIdx.y;
  const int t = si + (si >= bs ? 1 : 0);
  const int c0 = t * BB;
  const int j0 = bs * BB;
  const int tid = threadIdx.x;
  const float* src = ((bs == 0) ? covs : (const float*)S) + (size_t)k * DD * DD;
  float* dst = S + (size_t)k * DD * DD;

  __shared__ __align__(16) float Pl[BB][BB + 4];
  __shared__ __align__(16) float SJ[BB][BB + 4];
  __shared__ __align__(16) float Tl[BB][BB + 4];

  const float* Pb = Plbuf + (size_t)k * BB * BB;
  #pragma unroll
  for (int q = 0; q < 8; ++q) {
    int e = q * 512 + tid;
    int r = e >> 6, c = e & 63;
    Pl[r][c] = Pb[e];
    SJ[r][c] = src[(size_t)(j0 + r) * DD + c0 + c];
  }
  __syncthreads();

  // ---- T' = Pl * SJ  (thread: col c, 8 rows)
  {
    const int c = tid & 63;
    const int rg = (tid >> 6) * 8;
    float tv[8];
    #pragma unroll
    for (int r = 0; r < 8; ++r) tv[r] = 0.0f;
    for (int p = 0; p < BB; p += 4) {
      float s0 = SJ[p][c], s1 = SJ[p + 1][c], s2 = SJ[p + 2][c], s3 = SJ[p + 3][c];
      #pragma unroll
      for (int r = 0; r < 8; ++r) {
        float4 pv = *reinterpret_cast<const float4*>(&Pl[rg + r][p]);
        tv[r] = fmaf(pv.x, s0, fmaf(pv.y, s1, fmaf(pv.z, s2, fmaf(pv.w, s3, tv[r]))));
      }
    }
    #pragma unroll
    for (int r = 0; r < 8; ++r) Tl[rg + r][c] = tv[r];
  }
  __syncthreads();

  // ---- apply to this column slice (thread: row r, 32 cols)
  const int r = tid & 255;
  const int h = (tid >> 8) * 32;
  const bool inJ = (r >= j0) && (r < j0 + BB);  // wave-uniform
  if (inJ) {
    #pragma unroll
    for (int c = 0; c < 32; c += 4) {
      float4 tv4 = *reinterpret_cast<const float4*>(&Tl[r - j0][h + c]);
      float4 o = {-tv4.x, -tv4.y, -tv4.z, -tv4.w};
      *reinterpret_cast<float4*>(&dst[(size_t)r * DD + c0 + h + c]) = o;
    }
  } else {
    float Crow[BB];
    #pragma unroll
    for (int p = 0; p < BB; p += 4) {
      float4 cv = *reinterpret_cast<const float4*>(&src[(size_t)r * DD + j0 + p]);
      Crow[p] = cv.x; Crow[p + 1] = cv.y; Crow[p + 2] = cv.z; Crow[p + 3] = cv.w;
    }
    #pragma unroll
    for (int c = 0; c < 32; c += 4) {
      float4 acc = *reinterpret_cast<const float4*>(&src[(size_t)r * DD + c0 + h + c]);
      #pragma unroll
      for (int p = 0; p < BB; ++p) {
        float4 tv4 = *reinterpret_cast<const float4*>(&Tl[p][h + c]);
        acc.x = fmaf(Crow[p], tv4.x, acc.x);
        acc.y = fmaf(Crow[p], tv4.y, acc.y);
        acc.z = fmaf(Crow[p], tv4.z, acc.z);
        acc.w = fmaf(Crow[p], tv4.w, acc.w);
      }
      *reinterpret_cast<float4*>(&dst[(size_t)r * DD + c0 + h + c]) = acc;
    }
  }
}

// ---------------- Kernel 1c: final J3 defer + wv = S*mu + cA -----------------
// Body proven in r14; adapted to the r11 chain: -P3^{-1} read from Plbuf
// (written by pivot(3)), and the S[J3,J3] diag written here (r11's pivot(4)
// used to do it). C3 rows = pre-step-3 S values (last writer: update(2));
// J3-row values of cols <192 from update(3); wv's J3 columns served from LDS.
__global__ __launch_bounds__(512) void final_kernel(
    float* __restrict__ S, const float* __restrict__ Plbuf,
    const float* __restrict__ means, const float* __restrict__ counts,
    const int* __restrict__ n_points_p, const float* __restrict__ ldp,
    float* __restrict__ cA, float* __restrict__ wv)
{
  const int k = blockIdx.x;
  const int tid = threadIdx.x;
  float* Sk = S + (size_t)k * DD * DD;
  const float* Pb = Plbuf + (size_t)k * BB * BB;
  const int j3 = 3 * BB;  // 192

  __shared__ __align__(16) float Pl[BB][BB + 4];      // -P3^{-1}
  __shared__ __align__(16) float Dst[3 * BB][BB + 4]; // defer values rows 0..191
  __shared__ __align__(16) float mus[DD];
  __shared__ __align__(16) float red[2][DD];

  {
    const int rr = tid >> 3;
    const int cc = (tid & 7) * 8;
    *reinterpret_cast<float4*>(&Pl[rr][cc]) =
        *reinterpret_cast<const float4*>(&Pb[rr * BB + cc]);
    *reinterpret_cast<float4*>(&Pl[rr][cc + 4]) =
        *reinterpret_cast<const float4*>(&Pb[rr * BB + cc + 4]);
  }
  if (tid < DD) mus[tid] = means[(size_t)k * DD + tid];
  __syncthreads();

  // defer(3): rows r<192: M4[r,J3] = -(C3[r]*Pl); rows in J3: diag = Pl.
  {
    const int r = tid & 255;
    const int h = (tid >> 8) * 32;
    if (r < j3) {
      float Crw[BB];
      #pragma unroll
      for (int p = 0; p < BB; p += 4) {
        float4 cv = *reinterpret_cast<const float4*>(&Sk[(size_t)r * DD + j3 + p]);
        Crw[p] = cv.x; Crw[p + 1] = cv.y; Crw[p + 2] = cv.z; Crw[p + 3] = cv.w;
      }
      #pragma unroll
      for (int c = 0; c < 32; c += 4) {
        float a0 = 0.f, a1 = 0.f, a2 = 0.f, a3 = 0.f;
        #pragma unroll
        for (int p = 0; p < BB; ++p) {
          float4 pv = *reinterpret_cast<const float4*>(&Pl[p][h + c]);
          a0 = fmaf(Crw[p], pv.x, a0);
          a1 = fmaf(Crw[p], pv.y, a1);
          a2 = fmaf(Crw[p], pv.z, a2);
          a3 = fmaf(Crw[p], pv.w, a3);
        }
        float4 o = {-a0, -a1, -a2, -a3};
        *reinterpret_cast<float4*>(&Sk[(size_t)r * DD + j3 + h + c]) = o;
        *reinterpret_cast<float4*>(&Dst[r][h + c]) = o;
      }
    } else {
      #pragma unroll
      for (int c = 0; c < 32; c += 4) {
        *reinterpret_cast<float4*>(&Sk[(size_t)r * DD + j3 + h + c]) =
            *reinterpret_cast<const float4*>(&Pl[r - j3][h + c]);
      }
    }
  }
  __syncthreads();

  // wv_j = sum_i S[i,j] * mu_i ; J3 columns read from LDS (Dst/Pl), others
  // from global (final values, written in prior launches).
  {
    const int j = tid & 255;
    const int hp = tid >> 8;  // half: i in [hp*128, hp*128+128)
    float acc = 0.0f;
    if (j < j3) {
      const float* col = Sk + j;
      #pragma unroll 4
      for (int i = hp * 128; i < hp * 128 + 128; ++i)
        acc = fmaf(col[(size_t)i * DD], mus[i], acc);
    } else {
      const int jj = j - j3;
      if (hp == 0) {
        #pragma unroll 4
        for (int i = 0; i < 128; ++i) acc = fmaf(Dst[i][jj], mus[i], acc);
      } else {
        #pragma unroll 4
        for (int i = 128; i < 192; ++i) acc = fmaf(Dst[i][jj], mus[i], acc);
        #pragma unroll 4
        for (int i = 192; i < 256; ++i) acc = fmaf(Pl[i - 192][jj], mus[i], acc);
      }
    }
    red[hp][j] = acc;
  }
  __syncthreads();
  if (tid < DD) wv[(size_t)k * DD + tid] = red[0][tid] + red[1][tid];
  if (tid == 0) {
    float denom = (float)(*n_points_p) + 1.0f;  // ALPHA = 1
    float ld = ldp[k] + ldp[KC + k] + ldp[2 * KC + k] + ldp[3 * KC + k];
    // D*log(2*pi) = 256 * 1.8378770664093453
    cA[k] = logf(counts[k] / denom) - 0.5f * (470.49652900079047f + ld);
  }
}

// ---------------- Kernel 2: quad, wave-private barrier-free inner loop -------
// r11 proven form (407us, 74% VALU, 88 VGPR, no spill), KG=8: 512 blocks =
// exactly 2/CU -> ONE XT staging round per CU instead of two. r8/r10/r12:
// global-S caps at ~66-69% regardless of depth; r15: manual SW pipeline
// regressed (+34us) -- compiler scheduling of this loop is already optimal.
__global__ __launch_bounds__(256) void quad_kernel(
    const float* __restrict__ X, const float* __restrict__ means,
    const float* __restrict__ S, const float* __restrict__ cA,
    const float* __restrict__ wv, float* __restrict__ lp)
{
  __shared__ __align__(16) float XT[DD][NT];        // (i,r) at XT[i][r ^ (((i>>2)&15)<<2)]
  __shared__ __align__(16) float Pw[4][2][4][68];   // wave-private S strips; qred alias
  __shared__ __align__(16) float muw[2][DD];        // mu_k, wv_k
  __shared__ __align__(16) float lpb[KG][NT];       // results, flushed at end

  const int tid = threadIdx.x;
  const int n0 = blockIdx.x * NT;
  const int k0 = blockIdx.y * KG;

  // stage X tile transposed + swizzled (once per block)
  #pragma unroll
  for (int q = 0; q < 16; ++q) {
    int f = q * 1024 + tid * 4;
    int r = f >> 8;
    int c = f & 255;
    float4 xv = *reinterpret_cast<const float4*>(X + (size_t)(n0 + r) * DD + c);
    int rs = r ^ (((c >> 2) & 15) << 2);
    XT[c + 0][rs] = xv.x;
    XT[c + 1][rs] = xv.y;
    XT[c + 2][rs] = xv.z;
    XT[c + 3][rs] = xv.w;
  }

  const int tn = tid & 7;          // n sub-tile: rows tn*8 .. +7
  const int tj = tid >> 3;         // j sub-tile: cols tj*8 .. +7
  const int wid = tid >> 6;        // wave id 0..3
  const int lane = tid & 63;
  const int g = (tid >> 3) & 7;    // tj within wave
  const int srow = lane >> 4;      // staging row within 4-row chunk
  const int scol = (lane & 15) * 4;// staging col (float4)

  #pragma unroll 1
  for (int kk = 0; kk < KG; ++kk) {
    const int k = k0 + kk;
    const float* Skw = S + (size_t)k * DD * DD + wid * 64;  // wave's col slice

    __syncthreads();  // prev k's qred readers done (Pw aliased); XT staged
    muw[0][tid] = means[(size_t)k * DD + tid];
    muw[1][tid] = wv[(size_t)k * DD + tid];

    // prologue: chunk 0 -> LDS buf 0; chunk 1 -> prefetch regs
    float4 st = *reinterpret_cast<const float4*>(Skw + (size_t)srow * DD + scol);
    *reinterpret_cast<float4*>(&Pw[wid][0][srow][scol]) = st;
    st = *reinterpret_cast<const float4*>(Skw + (size_t)(4 + srow) * DD + scol);

    float y[8][8];
    #pragma unroll
    for (int a = 0; a < 8; ++a)
      #pragma unroll
      for (int b = 0; b < 8; ++b) y[a][b] = 0.0f;

    #pragma unroll 1
    for (int ct = 0; ct < 64; ++ct) {
      const int cur = ct & 1;
      #pragma unroll
      for (int il = 0; il < 4; ++il) {
        const int i = ct * 4 + il;
        const int sw = ((i >> 2) & 15) << 2;
        float xv[8], pv[8];
        *reinterpret_cast<float4*>(&xv[0]) =
            *reinterpret_cast<const float4*>(&XT[i][(tn * 8) ^ sw]);
        *reinterpret_cast<float4*>(&xv[4]) =
            *reinterpret_cast<const float4*>(&XT[i][(tn * 8 + 4) ^ sw]);
        *reinterpret_cast<float4*>(&pv[0]) =
            *reinterpret_cast<const float4*>(&Pw[wid][cur][il][g * 8]);
        *reinterpret_cast<float4*>(&pv[4]) =
            *reinterpret_cast<const float4*>(&Pw[wid][cur][il][g * 8 + 4]);
        #pragma unroll
        for (int a = 0; a < 8; ++a)
          #pragma unroll
          for (int b = 0; b < 8; ++b)
            y[a][b] = fmaf(xv[a], pv[b], y[a][b]);
      }
      if (ct < 63) {
        // publish chunk ct+1 into the other buffer (wave-private, no barrier);
        // prefetch chunk ct+2 into regs (stays in flight across next 4 ils)
        *reinterpret_cast<float4*>(&Pw[wid][cur ^ 1][srow][scol]) = st;
        const int cnx = (ct + 2 < 64) ? (ct + 2) : 63;
        st = *reinterpret_cast<const float4*>(
            Skw + (size_t)(cnx * 4 + srow) * DD + scol);
      }
    }
    __syncthreads();  // muw visible; all waves done with Pw before qred reuse

    // epilogue: q'[n] = sum_j (x[n,j]-mu_j) * (y[n,j]-wv_j), partial over 8 j
    float s[8];
    #pragma unroll
    for (int a = 0; a < 8; ++a) s[a] = 0.0f;
    #pragma unroll
    for (int b = 0; b < 8; ++b) {
      const int j = tj * 8 + b;
      const int swj = ((j >> 2) & 15) << 2;
      float dv[8];
      *reinterpret_cast<float4*>(&dv[0]) =
          *reinterpret_cast<const float4*>(&XT[j][(tn * 8) ^ swj]);
      *reinterpret_cast<float4*>(&dv[4]) =
          *reinterpret_cast<const float4*>(&XT[j][(tn * 8 + 4) ^ swj]);
      const float mj = muw[0][j];
      const float wj = muw[1][j];
      #pragma unroll
      for (int a = 0; a < 8; ++a)
        s[a] = fmaf(dv[a] - mj, y[a][b] - wj, s[a]);
    }

    float* qred = &Pw[0][0][0][0];  // 2048 floats needed; Pw (2176) dead now
    *reinterpret_cast<float4*>(&qred[tj * 64 + tn * 8]) =
        *reinterpret_cast<const float4*>(&s[0]);
    *reinterpret_cast<float4*>(&qred[tj * 64 + tn * 8 + 4]) =
        *reinterpret_cast<const float4*>(&s[4]);
    __syncthreads();
    if (tid < 64) {
      float qa = 0.f, qb = 0.f, qc = 0.f, qd = 0.f;
      #pragma unroll
      for (int t = 0; t < 32; t += 4) {
        qa += qred[(t + 0) * 64 + tid];
        qb += qred[(t + 1) * 64 + tid];
        qc += qred[(t + 2) * 64 + tid];
        qd += qred[(t + 3) * 64 + tid];
      }
      // q' = dev^T S dev = -quad  ->  lp = cA + 0.5*q'
      lpb[kk][tid] = fmaf(0.5f, (qa + qb) + (qc + qd), cA[k]);
    }
  }

  // coalesced lp flush: 2 float4 per point row (8 k values)
  __syncthreads();
  if (tid < 128) {
    const int n = tid >> 1;
    const int h = (tid & 1) * 4;
    float4 o = {lpb[h + 0][n], lpb[h + 1][n], lpb[h + 2][n], lpb[h + 3][n]};
    *reinterpret_cast<float4*>(&lp[(size_t)(n0 + n) * KC + k0 + h]) = o;
  }
}

// ---------------- Kernel 3: row softmax over K+1 = 65 entries -----------------
__global__ __launch_bounds__(64) void softmax_kernel(
    const float* __restrict__ lp, const int* __restrict__ n_points_p,
    float* __restrict__ out)
{
  const int n = blockIdx.x;
  const int l = threadIdx.x;
  const float denom = (float)(*n_points_p) + 1.0f;
  const float log_new = -logf(denom);  // log(ALPHA/denom), ALPHA=1

  float v = lp[(size_t)n * KC + l];
  float m = v;
  #pragma unroll
  for (int off = 32; off > 0; off >>= 1) m = fmaxf(m, __shfl_xor(m, off, 64));
  m = fmaxf(m, log_new);

  float e = expf(v - m);
  float s = e;
  #pragma unroll
  for (int off = 32; off > 0; off >>= 1) s += __shfl_xor(s, off, 64);
  float enew = expf(log_new - m);
  s += enew;

  out[(size_t)n * (KC + 1) + l] = e / s;
  if (l == 0) out[(size_t)n * (KC + 1) + KC] = enew / s;
}

extern "C" void kernel_launch(void* const* d_in, const int* in_sizes, int n_in,
                              void* d_out, int out_size, void* d_ws, size_t ws_size,
                              hipStream_t stream)
{
  const float* x       = (const float*)d_in[0];  // [N, D]
  const float* means   = (const float*)d_in[1];  // [K, D]
  const float* covs    = (const float*)d_in[2];  // [K, D, D]
  const float* counts  = (const float*)d_in[3];  // [K]
  const int*   n_points = (const int*)d_in[4];   // scalar

  float* S   = (float*)d_ws;                      // K*D*D
  float* cA  = S + (size_t)KC * DD * DD;          // K
  float* ldp = cA + KC;                           // 4*K
  float* lp  = ldp + 4 * KC;                      // N*K
  float* Plbuf = lp;  // alias: Plbuf (K*64*64 = N*K floats) used only during
                      // sweep; lp written only by quad afterwards.
  float* out = (float*)d_out;                     // [N, K+1]
  // wv = S_k*mu_k staged in the out buffer (64KB of 1MB); quad reads it before
  // softmax overwrites out — stream-ordered, safe.
  float* wv = out;

  for (int bs = 0; bs < 4; ++bs) {
    pivot_kernel<<<dim3(KC, 5), 512, 0, stream>>>(covs, S, Plbuf, ldp, bs);
    update_kernel<<<dim3(KC, 3), 512, 0, stream>>>(covs, S, Plbuf, bs);
  }
  final_kernel<<<KC, 512, 0, stream>>>(S, Plbuf, means, counts, n_points, ldp, cA, wv);
  quad_kernel<<<dim3(NPTS / NT, KC / KG), 256, 0, stream>>>(x, means, S, cA, wv, lp);
  softmax_kernel<<<NPTS, 64, 0, stream>>>(lp, n_points, out);
}

// Round 17
// 632.652 us; speedup vs baseline: 1.1750x; 1.0075x over previous
//
#include <hip/hip_runtime.h>
#include <math.h>

// StreamingDPM: probs = softmax([ -0.5*(D log2pi + logdet_k + quad_nk) + log_prior_k | log_new ])
// N=4096 D=256 K=64, out [N, K+1] fp32.
//
// ws layout (floats):
//   S    : K*D*D  (sweep result; holds -Sigma^{-1} after all steps)
//   cA   : K      (log_prior_k - 0.5*(D log2pi + logdet_k))
//   ldp  : 4*K    (per-block-step logdet partials)
//   lp   : N*K    (log-probs before softmax; ALIASED as Plbuf during sweep)
// wv (= S_k * mu_k, [K][D]) lives in the OUTPUT buffer temporarily (quad reads
// it before softmax overwrites out; stream-ordered, safe).
//
// Sweep: r11's proven multi-launch chain + r16's final_kernel fusion:
//   pivot(bs) x4  : defer J-cols of bs-1 (4 parallel blocks) + sweep P_bs.
//   update(bs) x4 : trailing update of the 3 non-J column slices.
//   final_kernel  : J3 defer (from Plbuf; values kept in LDS) + wv + cA.
// Rejected by measurement: cooperative fusion (r9, grid.sync ~70us), deep
// step fusion (r14, defer-path spill), manual quad SW pipeline (r15, +34us),
// quad KG=8 (r16, +10us), global-S quad paths (r8/r10/r12, cap 66-69%).

#define DD 256
#define KC 64
#define NPTS 4096
#define NT 64
#define BB 64          // sweep block size
#define KG 4           // clusters per quad block (r11 proven optimum)

// ---------------- Kernel 1a: pivot sweep + deferred J-col writeback ----------
__global__ __launch_bounds__(512) void pivot_kernel(
    const float* __restrict__ covs, float* __restrict__ S,
    float* __restrict__ Plbuf, float* __restrict__ ldp, int bs)
{
  const int k = blockIdx.x;
  const int by = blockIdx.y;
  const int tid = threadIdx.x;
  float* Pb = Plbuf + (size_t)k * BB * BB;

  __shared__ __align__(16) float Tl[BB][BB + 4];
  __shared__ __align__(16) float pivc[2][BB];
  __shared__ __align__(16) float pivr[2][BB];

  if (by < 4) {
    // ---- deferred write of step bs-1's J columns (rows r0..r0+63):
    //  M[J,J] = -P^{-1} = Pb ;  M[I,J] = C*P^{-1} = -(C*Pb)
    if (bs == 0) return;
    const int j0p = (bs - 1) * BB;
    const int r0 = by * BB;
    const float* src = ((bs == 1) ? covs : (const float*)S) + (size_t)k * DD * DD;
    float* dst = S + (size_t)k * DD * DD;

    const int rr = tid >> 3;         // 0..63
    const int cc = (tid & 7) * 8;    // 0..56
    *reinterpret_cast<float4*>(&Tl[rr][cc]) =
        *reinterpret_cast<const float4*>(&Pb[rr * BB + cc]);
    *reinterpret_cast<float4*>(&Tl[rr][cc + 4]) =
        *reinterpret_cast<const float4*>(&Pb[rr * BB + cc + 4]);
    __syncthreads();

    const int r = r0 + rr;
    if (r0 == j0p) {
      // rows in J: direct copy of -P^{-1}
      *reinterpret_cast<float4*>(&dst[(size_t)r * DD + j0p + cc]) =
          *reinterpret_cast<const float4*>(&Tl[rr][cc]);
      *reinterpret_cast<float4*>(&dst[(size_t)r * DD + j0p + cc + 4]) =
          *reinterpret_cast<const float4*>(&Tl[rr][cc + 4]);
    } else {
      float Crow[BB];
      #pragma unroll
      for (int p = 0; p < BB; p += 4) {
        float4 cv = *reinterpret_cast<const float4*>(&src[(size_t)r * DD + j0p + p]);
        Crow[p] = cv.x; Crow[p + 1] = cv.y; Crow[p + 2] = cv.z; Crow[p + 3] = cv.w;
      }
      float acc[8] = {0.f, 0.f, 0.f, 0.f, 0.f, 0.f, 0.f, 0.f};
      #pragma unroll
      for (int p = 0; p < BB; ++p) {
        float4 t0 = *reinterpret_cast<const float4*>(&Tl[p][cc]);
        float4 t1 = *reinterpret_cast<const float4*>(&Tl[p][cc + 4]);
        acc[0] = fmaf(Crow[p], t0.x, acc[0]);
        acc[1] = fmaf(Crow[p], t0.y, acc[1]);
        acc[2] = fmaf(Crow[p], t0.z, acc[2]);
        acc[3] = fmaf(Crow[p], t0.w, acc[3]);
        acc[4] = fmaf(Crow[p], t1.x, acc[4]);
        acc[5] = fmaf(Crow[p], t1.y, acc[5]);
        acc[6] = fmaf(Crow[p], t1.z, acc[6]);
        acc[7] = fmaf(Crow[p], t1.w, acc[7]);
      }
      float4 o0 = {-acc[0], -acc[1], -acc[2], -acc[3]};
      float4 o1 = {-acc[4], -acc[5], -acc[6], -acc[7]};
      *reinterpret_cast<float4*>(&dst[(size_t)r * DD + j0p + cc]) = o0;
      *reinterpret_cast<float4*>(&dst[(size_t)r * DD + j0p + cc + 4]) = o1;
    }
    return;
  }

  // ---- register-resident sweep of P = S[J,J] (step 0: from covs).
  // Thread owns row pr, cols pc..pc+7 in VGPRs for all 64 pivots; only the
  // pivot row/col is exchanged via double-buffered LDS. 1 barrier per pivot.
  const int j0 = bs * BB;
  const float* psrc = ((bs == 0) ? covs : (const float*)S) + (size_t)k * DD * DD;
  const int pr = tid >> 3;
  const int pc = (tid & 7) * 8;

  float v[8];
  {
    float4 a4 = *reinterpret_cast<const float4*>(&psrc[(size_t)(j0 + pr) * DD + j0 + pc]);
    float4 b4 = *reinterpret_cast<const float4*>(&psrc[(size_t)(j0 + pr) * DD + j0 + pc + 4]);
    v[0] = a4.x; v[1] = a4.y; v[2] = a4.z; v[3] = a4.w;
    v[4] = b4.x; v[5] = b4.y; v[6] = b4.z; v[7] = b4.w;
  }
  if (pc == 0) pivc[0][pr] = v[0];
  if (pr == 0) {
    #pragma unroll
    for (int e = 0; e < 8; ++e) pivr[0][pc + e] = v[e];
  }
  __syncthreads();

  float ld = 0.0f;
  #pragma unroll 1
  for (int p = 0; p < BB; ++p) {
    const int cur = p & 1, nxt = cur ^ 1;
    const float d = pivc[cur][p];
    const float inv_d = 1.0f / d;
    if (tid == 0) ld += logf(d);
    const float cr = pivc[cur][pr];
    float rw[8];
    *reinterpret_cast<float4*>(&rw[0]) = *reinterpret_cast<const float4*>(&pivr[cur][pc]);
    *reinterpret_cast<float4*>(&rw[4]) = *reinterpret_cast<const float4*>(&pivr[cur][pc + 4]);
    #pragma unroll
    for (int e = 0; e < 8; ++e) {
      float ge = fmaf(-inv_d * cr, rw[e], v[e]);         // general update
      if (pr == p)     ge = rw[e] * inv_d;               // pivot row
      if (pc + e == p) ge = (pr == p) ? -inv_d : cr * inv_d;  // pivot col/diag
      v[e] = ge;
    }
    if (p < BB - 1) {
      if (pr == p + 1) {
        #pragma unroll
        for (int e = 0; e < 8; ++e) pivr[nxt][pc + e] = v[e];
      }
      if (pc <= p + 1 && p + 1 < pc + 8) pivc[nxt][pr] = v[p + 1 - pc];
    }
    __syncthreads();
  }

  // store -P^{-1} for the update/deferred kernels (coalesced)
  float4 s0 = {v[0], v[1], v[2], v[3]};
  float4 s1 = {v[4], v[5], v[6], v[7]};
  *reinterpret_cast<float4*>(&Pb[pr * BB + pc]) = s0;
  *reinterpret_cast<float4*>(&Pb[pr * BB + pc + 4]) = s1;
  if (tid == 0) ldp[bs * KC + k] = ld;
}

// ---------------- Kernel 1b: trailing update of one non-J column slice ------
__global__ __launch_bounds__(512) void update_kernel(
    const float* __restrict__ covs, float* __restrict__ S,
    const float* __restrict__ Plbuf, int bs)
{
  const int k = blockIdx.x;
  const int si = blockIdx.y;
  const int t = si + (si >= bs ? 1 : 0);
  const int c0 = t * BB;
  const int j0 = bs * BB;
  const int tid = threadIdx.x;
  const float* src = ((bs == 0) ? covs : (const float*)S) + (size_t)k * DD * DD;
  float* dst = S + (size_t)k * DD * DD;

  __shared__ __align__(16) float Pl[BB][BB + 4];
  __shared__ __align__(16) float SJ[BB][BB + 4];
  __shared__ __align__(16) float Tl[BB][BB + 4];

  const float* Pb = Plbuf + (size_t)k * BB * BB;
  #pragma unroll
  for (int q = 0; q < 8; ++q) {
    int e = q * 512 + tid;
    int r = e >> 6, c = e & 63;
    Pl[r][c] = Pb[e];
    SJ[r][c] = src[(size_t)(j0 + r) * DD + c0 + c];
  }
  __syncthreads();

  // ---- T' = Pl * SJ  (thread: col c, 8 rows)
  {
    const int c = tid & 63;
    const int rg = (tid >> 6) * 8;
    float tv[8];
    #pragma unroll
    for (int r = 0; r < 8; ++r) tv[r] = 0.0f;
    for (int p = 0; p < BB; p += 4) {
      float s0 = SJ[p][c], s1 = SJ[p + 1][c], s2 = SJ[p + 2][c], s3 = SJ[p + 3][c];
      #pragma unroll
      for (int r = 0; r < 8; ++r) {
        float4 pv = *reinterpret_cast<const float4*>(&Pl[rg + r][p]);
        tv[r] = fmaf(pv.x, s0, fmaf(pv.y, s1, fmaf(pv.z, s2, fmaf(pv.w, s3, tv[r]))));
      }
    }
    #pragma unroll
    for (int r = 0; r < 8; ++r) Tl[rg + r][c] = tv[r];
  }
  __syncthreads();

  // ---- apply to this column slice (thread: row r, 32 cols)
  const int r = tid & 255;
  const int h = (tid >> 8) * 32;
  const bool inJ = (r >= j0) && (r < j0 + BB);  // wave-uniform
  if (inJ) {
    #pragma unroll
    for (int c = 0; c < 32; c += 4) {
      float4 tv4 = *reinterpret_cast<const float4*>(&Tl[r - j0][h + c]);
      float4 o = {-tv4.x, -tv4.y, -tv4.z, -tv4.w};
      *reinterpret_cast<float4*>(&dst[(size_t)r * DD + c0 + h + c]) = o;
    }
  } else {
    float Crow[BB];
    #pragma unroll
    for (int p = 0; p < BB; p += 4) {
      float4 cv = *reinterpret_cast<const float4*>(&src[(size_t)r * DD + j0 + p]);
      Crow[p] = cv.x; Crow[p + 1] = cv.y; Crow[p + 2] = cv.z; Crow[p + 3] = cv.w;
    }
    #pragma unroll
    for (int c = 0; c < 32; c += 4) {
      float4 acc = *reinterpret_cast<const float4*>(&src[(size_t)r * DD + c0 + h + c]);
      #pragma unroll
      for (int p = 0; p < BB; ++p) {
        float4 tv4 = *reinterpret_cast<const float4*>(&Tl[p][h + c]);
        acc.x = fmaf(Crow[p], tv4.x, acc.x);
        acc.y = fmaf(Crow[p], tv4.y, acc.y);
        acc.z = fmaf(Crow[p], tv4.z, acc.z);
        acc.w = fmaf(Crow[p], tv4.w, acc.w);
      }
      *reinterpret_cast<float4*>(&dst[(size_t)r * DD + c0 + h + c]) = acc;
    }
  }
}

// ---------------- Kernel 1c: final J3 defer + wv = S*mu + cA -----------------
__global__ __launch_bounds__(512) void final_kernel(
    float* __restrict__ S, const float* __restrict__ Plbuf,
    const float* __restrict__ means, const float* __restrict__ counts,
    const int* __restrict__ n_points_p, const float* __restrict__ ldp,
    float* __restrict__ cA, float* __restrict__ wv)
{
  const int k = blockIdx.x;
  const int tid = threadIdx.x;
  float* Sk = S + (size_t)k * DD * DD;
  const float* Pb = Plbuf + (size_t)k * BB * BB;
  const int j3 = 3 * BB;  // 192

  __shared__ __align__(16) float Pl[BB][BB + 4];      // -P3^{-1}
  __shared__ __align__(16) float Dst[3 * BB][BB + 4]; // defer values rows 0..191
  __shared__ __align__(16) float mus[DD];
  __shared__ __align__(16) float red[2][DD];

  {
    const int rr = tid >> 3;
    const int cc = (tid & 7) * 8;
    *reinterpret_cast<float4*>(&Pl[rr][cc]) =
        *reinterpret_cast<const float4*>(&Pb[rr * BB + cc]);
    *reinterpret_cast<float4*>(&Pl[rr][cc + 4]) =
        *reinterpret_cast<const float4*>(&Pb[rr * BB + cc + 4]);
  }
  if (tid < DD) mus[tid] = means[(size_t)k * DD + tid];
  __syncthreads();

  // defer(3): rows r<192: M4[r,J3] = -(C3[r]*Pl); rows in J3: diag = Pl.
  {
    const int r = tid & 255;
    const int h = (tid >> 8) * 32;
    if (r < j3) {
      float Crw[BB];
      #pragma unroll
      for (int p = 0; p < BB; p += 4) {
        float4 cv = *reinterpret_cast<const float4*>(&Sk[(size_t)r * DD + j3 + p]);
        Crw[p] = cv.x; Crw[p + 1] = cv.y; Crw[p + 2] = cv.z; Crw[p + 3] = cv.w;
      }
      #pragma unroll
      for (int c = 0; c < 32; c += 4) {
        float a0 = 0.f, a1 = 0.f, a2 = 0.f, a3 = 0.f;
        #pragma unroll
        for (int p = 0; p < BB; ++p) {
          float4 pv = *reinterpret_cast<const float4*>(&Pl[p][h + c]);
          a0 = fmaf(Crw[p], pv.x, a0);
          a1 = fmaf(Crw[p], pv.y, a1);
          a2 = fmaf(Crw[p], pv.z, a2);
          a3 = fmaf(Crw[p], pv.w, a3);
        }
        float4 o = {-a0, -a1, -a2, -a3};
        *reinterpret_cast<float4*>(&Sk[(size_t)r * DD + j3 + h + c]) = o;
        *reinterpret_cast<float4*>(&Dst[r][h + c]) = o;
      }
    } else {
      #pragma unroll
      for (int c = 0; c < 32; c += 4) {
        *reinterpret_cast<float4*>(&Sk[(size_t)r * DD + j3 + h + c]) =
            *reinterpret_cast<const float4*>(&Pl[r - j3][h + c]);
      }
    }
  }
  __syncthreads();

  // wv_j = sum_i S[i,j] * mu_i ; J3 columns read from LDS (Dst/Pl), others
  // from global (final values, written in prior launches).
  {
    const int j = tid & 255;
    const int hp = tid >> 8;  // half: i in [hp*128, hp*128+128)
    float acc = 0.0f;
    if (j < j3) {
      const float* col = Sk + j;
      #pragma unroll 4
      for (int i = hp * 128; i < hp * 128 + 128; ++i)
        acc = fmaf(col[(size_t)i * DD], mus[i], acc);
    } else {
      const int jj = j - j3;
      if (hp == 0) {
        #pragma unroll 4
        for (int i = 0; i < 128; ++i) acc = fmaf(Dst[i][jj], mus[i], acc);
      } else {
        #pragma unroll 4
        for (int i = 128; i < 192; ++i) acc = fmaf(Dst[i][jj], mus[i], acc);
        #pragma unroll 4
        for (int i = 192; i < 256; ++i) acc = fmaf(Pl[i - 192][jj], mus[i], acc);
      }
    }
    red[hp][j] = acc;
  }
  __syncthreads();
  if (tid < DD) wv[(size_t)k * DD + tid] = red[0][tid] + red[1][tid];
  if (tid == 0) {
    float denom = (float)(*n_points_p) + 1.0f;  // ALPHA = 1
    float ld = ldp[k] + ldp[KC + k] + ldp[2 * KC + k] + ldp[3 * KC + k];
    // D*log(2*pi) = 256 * 1.8378770664093453
    cA[k] = logf(counts[k] / denom) - 0.5f * (470.49652900079047f + ld);
  }
}

// ---------------- Kernel 2: quad, wave-private barrier-free inner loop -------
// r11 proven form VERBATIM (407us, 74% VALU, 88 VGPR, no spill, KG=4).
// Measured dead ends: global-S (r8/r10/r12: caps 66-69% at any pipeline
// depth), manual SW pipeline (r15: +34us), KG=8 (r16: +10us). Occupancy is
// algorithmically pinned at ~2 waves/SIMD: LDS/wave = D*4*points-per-wave
// = 16 KB/wave independent of tile size.
__global__ __launch_bounds__(256) void quad_kernel(
    const float* __restrict__ X, const float* __restrict__ means,
    const float* __restrict__ S, const float* __restrict__ cA,
    const float* __restrict__ wv, float* __restrict__ lp)
{
  __shared__ __align__(16) float XT[DD][NT];        // (i,r) at XT[i][r ^ (((i>>2)&15)<<2)]
  __shared__ __align__(16) float Pw[4][2][4][68];   // wave-private S strips; qred alias
  __shared__ __align__(16) float muw[2][DD];        // mu_k, wv_k
  __shared__ __align__(16) float lpb[KG][NT];       // results, flushed at end

  const int tid = threadIdx.x;
  const int n0 = blockIdx.x * NT;
  const int k0 = blockIdx.y * KG;

  // stage X tile transposed + swizzled (once per block)
  #pragma unroll
  for (int q = 0; q < 16; ++q) {
    int f = q * 1024 + tid * 4;
    int r = f >> 8;
    int c = f & 255;
    float4 xv = *reinterpret_cast<const float4*>(X + (size_t)(n0 + r) * DD + c);
    int rs = r ^ (((c >> 2) & 15) << 2);
    XT[c + 0][rs] = xv.x;
    XT[c + 1][rs] = xv.y;
    XT[c + 2][rs] = xv.z;
    XT[c + 3][rs] = xv.w;
  }

  const int tn = tid & 7;          // n sub-tile: rows tn*8 .. +7
  const int tj = tid >> 3;         // j sub-tile: cols tj*8 .. +7
  const int wid = tid >> 6;        // wave id 0..3
  const int lane = tid & 63;
  const int g = (tid >> 3) & 7;    // tj within wave
  const int srow = lane >> 4;      // staging row within 4-row chunk
  const int scol = (lane & 15) * 4;// staging col (float4)

  #pragma unroll 1
  for (int kk = 0; kk < KG; ++kk) {
    const int k = k0 + kk;
    const float* Skw = S + (size_t)k * DD * DD + wid * 64;  // wave's col slice

    __syncthreads();  // prev k's qred readers done (Pw aliased); XT staged
    muw[0][tid] = means[(size_t)k * DD + tid];
    muw[1][tid] = wv[(size_t)k * DD + tid];

    // prologue: chunk 0 -> LDS buf 0; chunk 1 -> prefetch regs
    float4 st = *reinterpret_cast<const float4*>(Skw + (size_t)srow * DD + scol);
    *reinterpret_cast<float4*>(&Pw[wid][0][srow][scol]) = st;
    st = *reinterpret_cast<const float4*>(Skw + (size_t)(4 + srow) * DD + scol);

    float y[8][8];
    #pragma unroll
    for (int a = 0; a < 8; ++a)
      #pragma unroll
      for (int b = 0; b < 8; ++b) y[a][b] = 0.0f;

    #pragma unroll 1
    for (int ct = 0; ct < 64; ++ct) {
      const int cur = ct & 1;
      #pragma unroll
      for (int il = 0; il < 4; ++il) {
        const int i = ct * 4 + il;
        const int sw = ((i >> 2) & 15) << 2;
        float xv[8], pv[8];
        *reinterpret_cast<float4*>(&xv[0]) =
            *reinterpret_cast<const float4*>(&XT[i][(tn * 8) ^ sw]);
        *reinterpret_cast<float4*>(&xv[4]) =
            *reinterpret_cast<const float4*>(&XT[i][(tn * 8 + 4) ^ sw]);
        *reinterpret_cast<float4*>(&pv[0]) =
            *reinterpret_cast<const float4*>(&Pw[wid][cur][il][g * 8]);
        *reinterpret_cast<float4*>(&pv[4]) =
            *reinterpret_cast<const float4*>(&Pw[wid][cur][il][g * 8 + 4]);
        #pragma unroll
        for (int a = 0; a < 8; ++a)
          #pragma unroll
          for (int b = 0; b < 8; ++b)
            y[a][b] = fmaf(xv[a], pv[b], y[a][b]);
      }
      if (ct < 63) {
        // publish chunk ct+1 into the other buffer (wave-private, no barrier);
        // prefetch chunk ct+2 into regs (stays in flight across next 4 ils)
        *reinterpret_cast<float4*>(&Pw[wid][cur ^ 1][srow][scol]) = st;
        const int cnx = (ct + 2 < 64) ? (ct + 2) : 63;
        st = *reinterpret_cast<const float4*>(
            Skw + (size_t)(cnx * 4 + srow) * DD + scol);
      }
    }
    __syncthreads();  // muw visible; all waves done with Pw before qred reuse

    // epilogue: q'[n] = sum_j (x[n,j]-mu_j) * (y[n,j]-wv_j), partial over 8 j
    float s[8];
    #pragma unroll
    for (int a = 0; a < 8; ++a) s[a] = 0.0f;
    #pragma unroll
    for (int b = 0; b < 8; ++b) {
      const int j = tj * 8 + b;
      const int swj = ((j >> 2) & 15) << 2;
      float dv[8];
      *reinterpret_cast<float4*>(&dv[0]) =
          *reinterpret_cast<const float4*>(&XT[j][(tn * 8) ^ swj]);
      *reinterpret_cast<float4*>(&dv[4]) =
          *reinterpret_cast<const float4*>(&XT[j][(tn * 8 + 4) ^ swj]);
      const float mj = muw[0][j];
      const float wj = muw[1][j];
      #pragma unroll
      for (int a = 0; a < 8; ++a)
        s[a] = fmaf(dv[a] - mj, y[a][b] - wj, s[a]);
    }

    float* qred = &Pw[0][0][0][0];  // 2048 floats needed; Pw (2176) dead now
    *reinterpret_cast<float4*>(&qred[tj * 64 + tn * 8]) =
        *reinterpret_cast<const float4*>(&s[0]);
    *reinterpret_cast<float4*>(&qred[tj * 64 + tn * 8 + 4]) =
        *reinterpret_cast<const float4*>(&s[4]);
    __syncthreads();
    if (tid < 64) {
      float qa = 0.f, qb = 0.f, qc = 0.f, qd = 0.f;
      #pragma unroll
      for (int t = 0; t < 32; t += 4) {
        qa += qred[(t + 0) * 64 + tid];
        qb += qred[(t + 1) * 64 + tid];
        qc += qred[(t + 2) * 64 + tid];
        qd += qred[(t + 3) * 64 + tid];
      }
      // q' = dev^T S dev = -quad  ->  lp = cA + 0.5*q'
      lpb[kk][tid] = fmaf(0.5f, (qa + qb) + (qc + qd), cA[k]);
    }
  }

  // lp flush: one float4 of 4 k-values per point row
  __syncthreads();
  if (tid < 64) {
    float4 o = {lpb[0][tid], lpb[1][tid], lpb[2][tid], lpb[3][tid]};
    *reinterpret_cast<float4*>(&lp[(size_t)(n0 + tid) * KC + k0]) = o;
  }
}

// ---------------- Kernel 3: row softmax over K+1 = 65 entries -----------------
__global__ __launch_bounds__(64) void softmax_kernel(
    const float* __restrict__ lp, const int* __restrict__ n_points_p,
    float* __restrict__ out)
{
  const int n = blockIdx.x;
  const int l = threadIdx.x;
  const float denom = (float)(*n_points_p) + 1.0f;
  const float log_new = -logf(denom);  // log(ALPHA/denom), ALPHA=1

  float v = lp[(size_t)n * KC + l];
  float m = v;
  #pragma unroll
  for (int off = 32; off > 0; off >>= 1) m = fmaxf(m, __shfl_xor(m, off, 64));
  m = fmaxf(m, log_new);

  float e = expf(v - m);
  float s = e;
  #pragma unroll
  for (int off = 32; off > 0; off >>= 1) s += __shfl_xor(s, off, 64);
  float enew = expf(log_new - m);
  s += enew;

  out[(size_t)n * (KC + 1) + l] = e / s;
  if (l == 0) out[(size_t)n * (KC + 1) + KC] = enew / s;
}

extern "C" void kernel_launch(void* const* d_in, const int* in_sizes, int n_in,
                              void* d_out, int out_size, void* d_ws, size_t ws_size,
                              hipStream_t stream)
{
  const float* x       = (const float*)d_in[0];  // [N, D]
  const float* means   = (const float*)d_in[1];  // [K, D]
  const float* covs    = (const float*)d_in[2];  // [K, D, D]
  const float* counts  = (const float*)d_in[3];  // [K]
  const int*   n_points = (const int*)d_in[4];   // scalar

  float* S   = (float*)d_ws;                      // K*D*D
  float* cA  = S + (size_t)KC * DD * DD;          // K
  float* ldp = cA + KC;                           // 4*K
  float* lp  = ldp + 4 * KC;                      // N*K
  float* Plbuf = lp;  // alias: Plbuf (K*64*64 = N*K floats) used only during
                      // sweep; lp written only by quad afterwards.
  float* out = (float*)d_out;                     // [N, K+1]
  // wv = S_k*mu_k staged in the out buffer (64KB of 1MB); quad reads it before
  // softmax overwrites out — stream-ordered, safe.
  float* wv = out;

  for (int bs = 0; bs < 4; ++bs) {
    pivot_kernel<<<dim3(KC, 5), 512, 0, stream>>>(covs, S, Plbuf, ldp, bs);
    update_kernel<<<dim3(KC, 3), 512, 0, stream>>>(covs, S, Plbuf, bs);
  }
  final_kernel<<<KC, 512, 0, stream>>>(S, Plbuf, means, counts, n_points, ldp, cA, wv);
  quad_kernel<<<dim3(NPTS / NT, KC / KG), 256, 0, stream>>>(x, means, S, cA, wv, lp);
  softmax_kernel<<<NPTS, 64, 0, stream>>>(lp, n_points, out);
}